// Round 5
// baseline (1857.312 us; speedup 1.0000x reference)
//
#include <hip/hip_runtime.h>
#include <hip/hip_bf16.h>

#define NE 512

// ---------------- static device buffers (avoid d_ws dependence) ----------------
__device__ __align__(16) float g_p[2][NE*NE*64];     // ping-pong pair features (67MB each)
__device__ __align__(16) float g_sv0[NE*64];
__device__ __align__(16) float g_sv[2][NE*256];
__device__ __align__(16) float g_pu4[NE*4];
__device__ __align__(16) float g_pd4[NE*4];
__device__ __align__(16) float g_pu[NE*64];
__device__ __align__(16) float g_pd[NE*64];
__device__ __align__(16) float g_su0[64];
__device__ __align__(16) float g_sd0[64];
__device__ __align__(16) float g_su[256];
__device__ __align__(16) float g_sd[256];
__device__ __align__(16) float g_part[8*NE*64];      // per-(j,chunk) partial means of p
__device__ __align__(16) float g_f[NE];              // sum_a exp(-|r_i - a|)
__device__ __align__(16) float g_hu[256*256];
__device__ __align__(16) float g_hd[256*256];
__device__ __align__(16) float g_orbu[256*256];
__device__ __align__(16) float g_orbd[256*256];
__device__ float g_logs[2];

__device__ __forceinline__ float tanh_fast(float x) {
  float e = __expf(2.f * x);
  return 1.f - 2.f / (e + 1.f);
}

// ---------------- K0: geometry -> s_v0, f, su0/sd0 ----------------
__global__ __launch_bounds__(512) void k_geom(const float* __restrict__ r,
                                              const float* __restrict__ a) {
  int e = threadIdx.x;
  float rx = r[3*e], ry = r[3*e+1], rz = r[3*e+2];
  float facc = 0.f;
  #pragma unroll
  for (int at = 0; at < 16; ++at) {
    float dx = rx - a[3*at], dy = ry - a[3*at+1], dz = rz - a[3*at+2];
    float len = sqrtf(dx*dx + dy*dy + dz*dz);
    g_sv0[e*64 + 4*at + 0] = dx;
    g_sv0[e*64 + 4*at + 1] = dy;
    g_sv0[e*64 + 4*at + 2] = dz;
    g_sv0[e*64 + 4*at + 3] = len;
    facc += expf(-len);
  }
  g_f[e] = facc;
  __syncthreads();            // global writes visible within block after barrier
  if (e < 128) {
    int h = e >> 6, c = e & 63;
    float s = 0.f;
    for (int i = 0; i < 256; ++i) s += g_sv0[(h*256 + i)*64 + c];
    (h ? g_sd0 : g_su0)[c] = s * (1.f/256.f);
  }
}

// ---------------- K0b: means of p0 (4-dim geometry pairs) ----------------
__global__ __launch_bounds__(256) void k_pmean0(const float* __restrict__ r) {
  int j = blockIdx.x, t = threadIdx.x;
  float rjx = r[3*j], rjy = r[3*j+1], rjz = r[3*j+2];
  __shared__ float red[4][4];
  for (int h = 0; h < 2; ++h) {
    int i = h*256 + t;
    float dx = rjx - r[3*i], dy = rjy - r[3*i+1], dz = rjz - r[3*i+2];
    float ee = (i == j) ? 1.f : 0.f;
    float ex = dx+ee, ey = dy+ee, ez = dz+ee;
    float len = sqrtf(ex*ex + ey*ey + ez*ez);
    float v0 = dx, v1 = dy, v2 = dz, v3 = len;
    #pragma unroll
    for (int m = 1; m < 64; m <<= 1) {
      v0 += __shfl_xor(v0, m); v1 += __shfl_xor(v1, m);
      v2 += __shfl_xor(v2, m); v3 += __shfl_xor(v3, m);
    }
    if ((t & 63) == 0) {
      int wv = t >> 6;
      red[wv][0]=v0; red[wv][1]=v1; red[wv][2]=v2; red[wv][3]=v3;
    }
    __syncthreads();
    if (t == 0) {
      float* dst = h ? g_pd4 : g_pu4;
      #pragma unroll
      for (int c = 0; c < 4; ++c)
        dst[j*4 + c] = (red[0][c]+red[1][c]+red[2][c]+red[3][c]) * (1.f/256.f);
    }
    __syncthreads();
  }
}

// ---------------- p-channel update. MODE 0: from geometry; 1: load+store; 2: load only ----
template<int MODE>
__global__ __launch_bounds__(256) void k_pup(const float* __restrict__ W,
                                             const float* __restrict__ Wb,
                                             const float* __restrict__ r,
                                             int src, int dst) {
  __shared__ __align__(16) float psh[4][64];
  int t = threadIdx.x, lane = t & 63, wv = t >> 6;
  int gw = blockIdx.x*4 + wv;          // 0..4095
  int j = gw >> 3, chunk = gw & 7;
  int i0 = chunk * 64;
  float macc = 0.f;
  if (MODE == 0) {
    float w0 = W[lane], w1 = W[64+lane], w2 = W[128+lane], w3 = W[192+lane];
    float bb = Wb[lane];
    float rjx = r[3*j], rjy = r[3*j+1], rjz = r[3*j+2];
    float* pout = g_p[0];
    for (int ii = 0; ii < 64; ++ii) {
      int i = i0 + ii;
      float dx = rjx - r[3*i], dy = rjy - r[3*i+1], dz = rjz - r[3*i+2];
      float ee = (i == j) ? 1.f : 0.f;
      float ex = dx+ee, ey = dy+ee, ez = dz+ee;
      float len = sqrtf(ex*ex + ey*ey + ez*ez);
      float y = tanh_fast(bb + dx*w0 + dy*w1 + dz*w2 + len*w3);
      pout[(i*NE + j)*64 + lane] = y;
      macc += y;
    }
  } else {
    const float* pin = g_p[src];
    float* pout = g_p[dst];
    float wcol[64];
    #pragma unroll
    for (int k = 0; k < 64; ++k) wcol[k] = W[k*64 + lane];
    float bb = Wb[lane];
    for (int ii = 0; ii < 64; ++ii) {
      int i = i0 + ii;
      int base = (i*NE + j)*64;
      float x = pin[base + lane];
      psh[wv][lane] = x;
      float acc = bb;
      #pragma unroll
      for (int g = 0; g < 16; ++g) {
        float4 pv = *(const float4*)&psh[wv][4*g];   // wave-uniform broadcast reads
        acc += pv.x*wcol[4*g] + pv.y*wcol[4*g+1] + pv.z*wcol[4*g+2] + pv.w*wcol[4*g+3];
      }
      float y = tanh_fast(acc) + x;                  // residual (layers >= 1)
      if (MODE == 1) pout[base + lane] = y;
      macc += y;
    }
  }
  g_part[chunk*(NE*64) + j*64 + lane] = macc;
}

// ---------------- finalize p-means + s-means ----------------
__global__ __launch_bounds__(256) void k_reduce(int svsel) {
  int bid = blockIdx.x, t = threadIdx.x;
  if (bid < 256) {
    int idx = bid*256 + t;
    int half = idx >> 15, rem = idx & 32767;
    int j = rem >> 6, l = rem & 63;
    const float* pp = g_part + half*(4*NE*64);
    float s = pp[0*(NE*64)+j*64+l] + pp[1*(NE*64)+j*64+l]
            + pp[2*(NE*64)+j*64+l] + pp[3*(NE*64)+j*64+l];
    (half ? g_pd : g_pu)[j*64 + l] = s * (1.f/256.f);
  } else {
    int h = bid - 256;
    const float* sv = g_sv[svsel];
    float s = 0.f;
    for (int i = 0; i < 256; ++i) s += sv[(h*256 + i)*256 + t];
    (h ? g_sd : g_su)[t] = s * (1.f/256.f);
  }
}

// ---------------- generic s-channel matmul (layers / heads / orbitals) ----------------
// which: 0=layer0, 1..3=layer l, 4=head_u, 5=head_d, 6=orb_u, 7=orb_d
template<int PUK, int SVK, int MEANK>
__global__ __launch_bounds__(256) void k_smm(int which, const float* __restrict__ W,
                                             const float* __restrict__ Wb) {
  constexpr int MAINK = 2*PUK + SVK;
  __shared__ __align__(16) float wsl[MAINK*32];
  __shared__ float insl[32*(MAINK+1)];
  __shared__ float biasv[32];
  __shared__ float bred[256];
  const float *pu_p=nullptr, *pd_p=nullptr, *sv_p=nullptr, *su_p=nullptr, *sd_p=nullptr;
  const float *res_p=nullptr, *rs_p=nullptr;
  float* out_p = nullptr;
  int row0 = 0, dotanh = 1;
  switch (which) {
    case 0: pu_p=g_pu4; pd_p=g_pd4; su_p=g_su0; sd_p=g_sd0; sv_p=g_sv0; out_p=g_sv[0]; break;
    case 1: case 2: case 3:
      pu_p=g_pu; pd_p=g_pd; su_p=g_su; sd_p=g_sd;
      sv_p=g_sv[(which+1)&1]; res_p=sv_p; out_p=g_sv[which&1]; break;
    case 4: pu_p=g_pu; pd_p=g_pd; su_p=g_su; sd_p=g_sd; sv_p=g_sv[1]; out_p=g_hu; break;
    case 5: pu_p=g_pu; pd_p=g_pd; su_p=g_su; sd_p=g_sd; sv_p=g_sv[1]; out_p=g_hd; row0=256; break;
    case 6: sv_p=g_hu; out_p=g_orbu; rs_p=g_f;       dotanh=0; break;
    default: sv_p=g_hd; out_p=g_orbd; rs_p=g_f+256;  dotanh=0; break;
  }
  int t = threadIdx.x;
  int rg = blockIdx.x, cg = blockIdx.y;
  int col0 = cg * 32;
  for (int idx = t; idx < MAINK*32; idx += 256) {
    int c = idx >> 5, cl = idx & 31;
    wsl[idx] = W[(2*MEANK + c)*256 + col0 + cl];
  }
  for (int rr = 0; rr < 32; ++rr) {
    int row = row0 + rg*32 + rr;
    for (int c = t; c < MAINK; c += 256) {
      float v;
      if (c < PUK) v = pu_p[row*PUK + c];
      else if (c < 2*PUK) v = pd_p[row*PUK + (c - PUK)];
      else v = sv_p[row*SVK + (c - 2*PUK)];
      insl[rr*(MAINK+1) + c] = v;
    }
  }
  {
    int pcol = t & 31, ps = t >> 5;
    float bacc = 0.f;
    if (MEANK > 0) {
      for (int c = ps; c < MEANK; c += 8)
        bacc += su_p[c]*W[c*256 + col0 + pcol] + sd_p[c]*W[(MEANK + c)*256 + col0 + pcol];
    }
    bred[ps*32 + pcol] = bacc;
  }
  __syncthreads();
  if (t < 32) {
    float s = Wb[col0 + t];
    #pragma unroll
    for (int p8 = 0; p8 < 8; ++p8) s += bred[p8*32 + t];
    biasv[t] = s;
  }
  __syncthreads();
  int c4 = t & 7, rl = t >> 3;
  float a0 = biasv[4*c4], a1 = biasv[4*c4+1], a2 = biasv[4*c4+2], a3 = biasv[4*c4+3];
  const float* inrow = &insl[rl*(MAINK+1)];
  for (int c = 0; c < MAINK; ++c) {
    float iv = inrow[c];
    float4 wv = *(const float4*)&wsl[c*32 + 4*c4];
    a0 += iv*wv.x; a1 += iv*wv.y; a2 += iv*wv.z; a3 += iv*wv.w;
  }
  int rowA = rg*32 + rl;
  int col = col0 + 4*c4;
  if (dotanh) { a0=tanh_fast(a0); a1=tanh_fast(a1); a2=tanh_fast(a2); a3=tanh_fast(a3); }
  if (res_p) {
    float4 rv = *(const float4*)&res_p[rowA*256 + col];
    a0 += rv.x; a1 += rv.y; a2 += rv.z; a3 += rv.w;
  }
  if (rs_p) { float fsc = rs_p[rowA]; a0*=fsc; a1*=fsc; a2*=fsc; a3*=fsc; }
  float4 ov; ov.x=a0; ov.y=a1; ov.z=a2; ov.w=a3;
  *(float4*)&out_p[rowA*256 + col] = ov;
}

// ---------------- blocked LU (NB=8), implicit partial pivoting (v5) ----------------
// R4 lesson: per-column critical chain (search + rank-1 + 2 bars) ~1200cy. v5 moves
// the rank-1 updates off the chain: per column only (a) owners produce column k with
// <=7 pending FMAs (Crout), (b) argmax, (c) owners publish pivot row with <=7 pending
// FMAs. Rank-8 apply once per 8 columns, trailing-cols only. mult/prow LDS buffers
// use 12/20-word group strides so reads stay <=2-way conflicted.
// Garbage containment: used rows excluded via per-thread um mask; |mult|<=1 for live
// rows (partial pivoting) so live rows stay finite; NaN confined to used rows /
// factored cols which are never read again.
#define REP8(M) M(0) M(1) M(2) M(3) M(4) M(5) M(6) M(7)

__global__ __launch_bounds__(512, 2) void k_lu() {
  __shared__ __align__(16) float colbuf[256];
  __shared__ __align__(16) float multb[8*384];   // mult[j][row]: j*384 + 12*(r>>3) + (r&7)
  __shared__ __align__(16) float prowb[8*320];   // prow[j][col]: j*320 + 20*(c>>4) + (c&15)
  const float* A = (blockIdx.x == 0) ? g_orbu : g_orbd;
  int t = threadIdx.x;
  int tile_r = t >> 4;        // 0..31 -> rows 8*tile_r .. +7
  int tile_c = t & 15;        // 0..15 -> cols 16*tile_c .. +15
  int lane = t & 63;
  const float4* Ap = (const float4*)(A + (tile_r*8)*256 + tile_c*16);
#define DECLROW(R) float4 M##R##_0 = Ap[R*64+0], M##R##_1 = Ap[R*64+1], \
                          M##R##_2 = Ap[R*64+2], M##R##_3 = Ap[R*64+3];
  REP8(DECLROW)
#undef DECLROW
  unsigned um = 0;            // used-mask for candidate rows 4*lane..4*lane+3
  float logsum = 0.f;
  for (int kb = 0; kb < 32; ++kb) {
    int k0 = kb * 8;
    for (int s = 0; s < 8; ++s) {
      int kk = k0 + s;
      // ---- phase C: column owners produce updated column kk ----
      if (tile_c == (kk >> 4)) {
        float e0,e1,e2,e3,e4,e5,e6,e7;
        switch (kk & 15) {
#define EXT(I,G,C) case I: e0=M0_##G.C; e1=M1_##G.C; e2=M2_##G.C; e3=M3_##G.C; \
                           e4=M4_##G.C; e5=M5_##G.C; e6=M6_##G.C; e7=M7_##G.C; break;
          EXT(0,0,x) EXT(1,0,y) EXT(2,0,z) EXT(3,0,w)
          EXT(4,1,x) EXT(5,1,y) EXT(6,1,z) EXT(7,1,w)
          EXT(8,2,x) EXT(9,2,y) EXT(10,2,z) EXT(11,2,w)
          EXT(12,3,x) EXT(13,3,y) EXT(14,3,z) EXT(15,3,w)
#undef EXT
        }
        #pragma unroll
        for (int j = 0; j < 7; ++j) {
          if (j < s) {
            float pv = prowb[j*320 + 20*(kk>>4) + (kk&15)];
            float4 ma = *(const float4*)&multb[j*384 + 12*tile_r];
            float4 mb = *(const float4*)&multb[j*384 + 12*tile_r + 4];
            e0 -= ma.x*pv; e1 -= ma.y*pv; e2 -= ma.z*pv; e3 -= ma.w*pv;
            e4 -= mb.x*pv; e5 -= mb.y*pv; e6 -= mb.z*pv; e7 -= mb.w*pv;
          }
        }
        int br = tile_r * 8;
        colbuf[br+0]=e0; colbuf[br+1]=e1; colbuf[br+2]=e2; colbuf[br+3]=e3;
        colbuf[br+4]=e4; colbuf[br+5]=e5; colbuf[br+6]=e6; colbuf[br+7]=e7;
      }
      __syncthreads();
      // ---- phase S: pivot search (all threads, redundant per wave) ----
      float4 cv = *(const float4*)&colbuf[4*lane];
      unsigned b0 = (um & 1u) ? 0u : ((__float_as_uint(fabsf(cv.x)) & 0xFFFFFF00u) | (unsigned)(4*lane+0));
      unsigned b1 = (um & 2u) ? 0u : ((__float_as_uint(fabsf(cv.y)) & 0xFFFFFF00u) | (unsigned)(4*lane+1));
      unsigned b2 = (um & 4u) ? 0u : ((__float_as_uint(fabsf(cv.z)) & 0xFFFFFF00u) | (unsigned)(4*lane+2));
      unsigned b3 = (um & 8u) ? 0u : ((__float_as_uint(fabsf(cv.w)) & 0xFFFFFF00u) | (unsigned)(4*lane+3));
      unsigned bb = max(max(b0,b1), max(b2,b3));
      #pragma unroll
      for (int m = 1; m < 64; m <<= 1) {
        unsigned ob = __shfl_xor(bb, m);
        bb = ob > bb ? ob : bb;
      }
      int p = (int)(bb & 255u);
      float piv = colbuf[p];
      logsum += __logf(fabsf(piv));
      float rp = 1.0f / piv;
      if ((p >> 2) == lane) um |= 1u << (p & 3);
      // multiplier column s for all rows
      if (t < 256) multb[s*384 + 12*(t>>3) + (t&7)] = colbuf[t] * rp;
      // pivot-row owners publish row p (with pending in-block updates applied)
      if (tile_r == (p >> 3)) {
        float4 P0, P1, P2, P3;
        switch (p & 7) {
#define CPY(R) case R: P0=M##R##_0; P1=M##R##_1; P2=M##R##_2; P3=M##R##_3; break;
          REP8(CPY)
#undef CPY
        }
        #pragma unroll
        for (int j = 0; j < 7; ++j) {
          if (j < s) {
            float mj = multb[j*384 + 12*(p>>3) + (p&7)];
            float4 q0 = *(const float4*)&prowb[j*320 + 20*tile_c + 0];
            float4 q1 = *(const float4*)&prowb[j*320 + 20*tile_c + 4];
            float4 q2 = *(const float4*)&prowb[j*320 + 20*tile_c + 8];
            float4 q3 = *(const float4*)&prowb[j*320 + 20*tile_c + 12];
            P0.x -= mj*q0.x; P0.y -= mj*q0.y; P0.z -= mj*q0.z; P0.w -= mj*q0.w;
            P1.x -= mj*q1.x; P1.y -= mj*q1.y; P1.z -= mj*q1.z; P1.w -= mj*q1.w;
            P2.x -= mj*q2.x; P2.y -= mj*q2.y; P2.z -= mj*q2.z; P2.w -= mj*q2.w;
            P3.x -= mj*q3.x; P3.y -= mj*q3.y; P3.z -= mj*q3.z; P3.w -= mj*q3.w;
          }
        }
        *(float4*)&prowb[s*320 + 20*tile_c + 0]  = P0;
        *(float4*)&prowb[s*320 + 20*tile_c + 4]  = P1;
        *(float4*)&prowb[s*320 + 20*tile_c + 8]  = P2;
        *(float4*)&prowb[s*320 + 20*tile_c + 12] = P3;
      }
      __syncthreads();
    }
    // ---- rank-8 apply to trailing columns (off the critical chain) ----
    if (kb < 31 && (tile_c*16 + 15) >= (k0 + 8)) {
      #pragma unroll
      for (int j = 0; j < 8; ++j) {
        float4 ma = *(const float4*)&multb[j*384 + 12*tile_r];
        float4 mb = *(const float4*)&multb[j*384 + 12*tile_r + 4];
        float4 q0 = *(const float4*)&prowb[j*320 + 20*tile_c + 0];
        float4 q1 = *(const float4*)&prowb[j*320 + 20*tile_c + 4];
        float4 q2 = *(const float4*)&prowb[j*320 + 20*tile_c + 8];
        float4 q3 = *(const float4*)&prowb[j*320 + 20*tile_c + 12];
#define UPDJ(R, MR) { float mr = MR; \
  M##R##_0.x -= mr*q0.x; M##R##_0.y -= mr*q0.y; M##R##_0.z -= mr*q0.z; M##R##_0.w -= mr*q0.w; \
  M##R##_1.x -= mr*q1.x; M##R##_1.y -= mr*q1.y; M##R##_1.z -= mr*q1.z; M##R##_1.w -= mr*q1.w; \
  M##R##_2.x -= mr*q2.x; M##R##_2.y -= mr*q2.y; M##R##_2.z -= mr*q2.z; M##R##_2.w -= mr*q2.w; \
  M##R##_3.x -= mr*q3.x; M##R##_3.y -= mr*q3.y; M##R##_3.z -= mr*q3.z; M##R##_3.w -= mr*q3.w; }
        UPDJ(0, ma.x) UPDJ(1, ma.y) UPDJ(2, ma.z) UPDJ(3, ma.w)
        UPDJ(4, mb.x) UPDJ(5, mb.y) UPDJ(6, mb.z) UPDJ(7, mb.w)
#undef UPDJ
      }
    }
    // no barrier needed: next writes to colbuf/multb/prowb occur only after the
    // next step's barrier, and every thread finishes apply before reaching it.
  }
  if (t == 0) g_logs[blockIdx.x] = logsum;
}

__global__ void k_final(float* out) { out[0] = g_logs[0] + g_logs[1]; }

// ---------------- launch ----------------
extern "C" void kernel_launch(void* const* d_in, const int* in_sizes, int n_in,
                              void* d_out, int out_size, void* d_ws, size_t ws_size,
                              hipStream_t stream) {
  const float* r     = (const float*)d_in[0];
  const float* a     = (const float*)d_in[1];
  const float* V0_W  = (const float*)d_in[2];
  const float* V0_b  = (const float*)d_in[3];
  const float* Vr_W  = (const float*)d_in[4];
  const float* Vr_b  = (const float*)d_in[5];
  const float* W0_W  = (const float*)d_in[6];
  const float* W0_b  = (const float*)d_in[7];
  const float* Wr_W  = (const float*)d_in[8];
  const float* Wr_b  = (const float*)d_in[9];
  const float* Vhu_W = (const float*)d_in[10];
  const float* Vhu_b = (const float*)d_in[11];
  const float* Vhd_W = (const float*)d_in[12];
  const float* Vhd_b = (const float*)d_in[13];
  const float* wu_W  = (const float*)d_in[14];
  const float* wu_b  = (const float*)d_in[15];
  const float* wd_W  = (const float*)d_in[16];
  const float* wd_b  = (const float*)d_in[17];
  float* out = (float*)d_out;

  k_geom<<<1, 512, 0, stream>>>(r, a);
  k_pmean0<<<512, 256, 0, stream>>>(r);

  // layer 0
  k_smm<4,64,64><<<dim3(16,8), 256, 0, stream>>>(0, V0_W, V0_b);
  k_pup<0><<<1024, 256, 0, stream>>>(W0_W, W0_b, r, 0, 0);
  k_reduce<<<258, 256, 0, stream>>>(0);
  // layer 1
  k_smm<64,256,256><<<dim3(16,8), 256, 0, stream>>>(1, Vr_W + 0*896*256, Vr_b + 0);
  k_pup<1><<<1024, 256, 0, stream>>>(Wr_W + 0*4096, Wr_b + 0, r, 0, 1);
  k_reduce<<<258, 256, 0, stream>>>(1);
  // layer 2
  k_smm<64,256,256><<<dim3(16,8), 256, 0, stream>>>(2, Vr_W + 1*896*256, Vr_b + 256);
  k_pup<1><<<1024, 256, 0, stream>>>(Wr_W + 1*4096, Wr_b + 64, r, 1, 0);
  k_reduce<<<258, 256, 0, stream>>>(0);
  // layer 3 (p4 not stored; only its means)
  k_smm<64,256,256><<<dim3(16,8), 256, 0, stream>>>(3, Vr_W + 2*896*256, Vr_b + 512);
  k_pup<2><<<1024, 256, 0, stream>>>(Wr_W + 2*4096, Wr_b + 128, r, 0, 0);
  k_reduce<<<258, 256, 0, stream>>>(1);
  // heads
  k_smm<64,256,256><<<dim3(8,8), 256, 0, stream>>>(4, Vhu_W, Vhu_b);
  k_smm<64,256,256><<<dim3(8,8), 256, 0, stream>>>(5, Vhd_W, Vhd_b);
  // orbitals
  k_smm<0,256,0><<<dim3(8,8), 256, 0, stream>>>(6, wu_W, wu_b);
  k_smm<0,256,0><<<dim3(8,8), 256, 0, stream>>>(7, wd_W, wd_b);
  // log|det| x2 and combine
  k_lu<<<2, 512, 0, stream>>>();
  k_final<<<1, 1, 0, stream>>>(out);
}

// Round 6
// 1029.206 us; speedup vs baseline: 1.8046x; 1.8046x over previous
//
#include <hip/hip_runtime.h>
#include <hip/hip_bf16.h>

#define NE 512

// ---------------- static device buffers (avoid d_ws dependence) ----------------
__device__ __align__(16) float g_p[2][NE*NE*64];     // ping-pong pair features (67MB each)
__device__ __align__(16) float g_sv0[NE*64];
__device__ __align__(16) float g_sv[2][NE*256];
__device__ __align__(16) float g_pu4[NE*4];
__device__ __align__(16) float g_pd4[NE*4];
__device__ __align__(16) float g_pu[NE*64];
__device__ __align__(16) float g_pd[NE*64];
__device__ __align__(16) float g_su0[64];
__device__ __align__(16) float g_sd0[64];
__device__ __align__(16) float g_su[256];
__device__ __align__(16) float g_sd[256];
__device__ __align__(16) float g_part[8*NE*64];      // per-(j,chunk) partial means of p
__device__ __align__(16) float g_f[NE];              // sum_a exp(-|r_i - a|)
__device__ __align__(16) float g_hu[256*256];
__device__ __align__(16) float g_hd[256*256];
__device__ __align__(16) float g_orbu[256*256];
__device__ __align__(16) float g_orbd[256*256];
__device__ float g_logs[2];

__device__ __forceinline__ float tanh_fast(float x) {
  float e = __expf(2.f * x);
  return 1.f - 2.f / (e + 1.f);
}

// ---------------- K0: geometry -> s_v0, f, su0/sd0 ----------------
__global__ __launch_bounds__(512) void k_geom(const float* __restrict__ r,
                                              const float* __restrict__ a) {
  int e = threadIdx.x;
  float rx = r[3*e], ry = r[3*e+1], rz = r[3*e+2];
  float facc = 0.f;
  #pragma unroll
  for (int at = 0; at < 16; ++at) {
    float dx = rx - a[3*at], dy = ry - a[3*at+1], dz = rz - a[3*at+2];
    float len = sqrtf(dx*dx + dy*dy + dz*dz);
    g_sv0[e*64 + 4*at + 0] = dx;
    g_sv0[e*64 + 4*at + 1] = dy;
    g_sv0[e*64 + 4*at + 2] = dz;
    g_sv0[e*64 + 4*at + 3] = len;
    facc += expf(-len);
  }
  g_f[e] = facc;
  __syncthreads();            // global writes visible within block after barrier
  if (e < 128) {
    int h = e >> 6, c = e & 63;
    float s = 0.f;
    for (int i = 0; i < 256; ++i) s += g_sv0[(h*256 + i)*64 + c];
    (h ? g_sd0 : g_su0)[c] = s * (1.f/256.f);
  }
}

// ---------------- K0b: means of p0 (4-dim geometry pairs) ----------------
__global__ __launch_bounds__(256) void k_pmean0(const float* __restrict__ r) {
  int j = blockIdx.x, t = threadIdx.x;
  float rjx = r[3*j], rjy = r[3*j+1], rjz = r[3*j+2];
  __shared__ float red[4][4];
  for (int h = 0; h < 2; ++h) {
    int i = h*256 + t;
    float dx = rjx - r[3*i], dy = rjy - r[3*i+1], dz = rjz - r[3*i+2];
    float ee = (i == j) ? 1.f : 0.f;
    float ex = dx+ee, ey = dy+ee, ez = dz+ee;
    float len = sqrtf(ex*ex + ey*ey + ez*ez);
    float v0 = dx, v1 = dy, v2 = dz, v3 = len;
    #pragma unroll
    for (int m = 1; m < 64; m <<= 1) {
      v0 += __shfl_xor(v0, m); v1 += __shfl_xor(v1, m);
      v2 += __shfl_xor(v2, m); v3 += __shfl_xor(v3, m);
    }
    if ((t & 63) == 0) {
      int wv = t >> 6;
      red[wv][0]=v0; red[wv][1]=v1; red[wv][2]=v2; red[wv][3]=v3;
    }
    __syncthreads();
    if (t == 0) {
      float* dst = h ? g_pd4 : g_pu4;
      #pragma unroll
      for (int c = 0; c < 4; ++c)
        dst[j*4 + c] = (red[0][c]+red[1][c]+red[2][c]+red[3][c]) * (1.f/256.f);
    }
    __syncthreads();
  }
}

// ---------------- p-channel update. MODE 0: from geometry; 1: load+store; 2: load only ----
// R5 change: the dot-product row is wave-uniform -> read it via readfirstlane'd
// base (scalar/broadcast loads, bypasses the LDS unit entirely). R4 est. ~80us/layer
// of ds_read_b128 issue cost eliminated.
template<int MODE>
__global__ __launch_bounds__(256) void k_pup(const float* __restrict__ W,
                                             const float* __restrict__ Wb,
                                             const float* __restrict__ r,
                                             int src, int dst) {
  int t = threadIdx.x, lane = t & 63, wv = t >> 6;
  int gw = blockIdx.x*4 + wv;          // 0..4095
  int j = gw >> 3, chunk = gw & 7;
  int i0 = chunk * 64;
  float macc = 0.f;
  if (MODE == 0) {
    float w0 = W[lane], w1 = W[64+lane], w2 = W[128+lane], w3 = W[192+lane];
    float bb = Wb[lane];
    float rjx = r[3*j], rjy = r[3*j+1], rjz = r[3*j+2];
    float* pout = g_p[0];
    for (int ii = 0; ii < 64; ++ii) {
      int i = i0 + ii;
      float dx = rjx - r[3*i], dy = rjy - r[3*i+1], dz = rjz - r[3*i+2];
      float ee = (i == j) ? 1.f : 0.f;
      float ex = dx+ee, ey = dy+ee, ez = dz+ee;
      float len = sqrtf(ex*ex + ey*ey + ez*ez);
      float y = tanh_fast(bb + dx*w0 + dy*w1 + dz*w2 + len*w3);
      pout[(i*NE + j)*64 + lane] = y;
      macc += y;
    }
  } else {
    const float* pin = g_p[src];
    float* pout = g_p[dst];
    float wcol[64];
    #pragma unroll
    for (int k = 0; k < 64; ++k) wcol[k] = W[k*64 + lane];
    float bb = Wb[lane];
    for (int ii = 0; ii < 64; ++ii) {
      int i = i0 + ii;
      int base = (i*NE + j)*64;
      int sbase = __builtin_amdgcn_readfirstlane(base);
      const float4* srow = (const float4*)(pin + sbase);
      float x = pin[base + lane];
      float acc = bb;
      #pragma unroll
      for (int g = 0; g < 16; ++g) {
        float4 pv = srow[g];               // wave-uniform broadcast loads
        acc += pv.x*wcol[4*g] + pv.y*wcol[4*g+1] + pv.z*wcol[4*g+2] + pv.w*wcol[4*g+3];
      }
      float y = tanh_fast(acc) + x;        // residual (layers >= 1)
      if (MODE == 1) pout[base + lane] = y;
      macc += y;
    }
  }
  g_part[chunk*(NE*64) + j*64 + lane] = macc;
}

// ---------------- finalize p-means + s-means ----------------
__global__ __launch_bounds__(256) void k_reduce(int svsel) {
  int bid = blockIdx.x, t = threadIdx.x;
  if (bid < 256) {
    int idx = bid*256 + t;
    int half = idx >> 15, rem = idx & 32767;
    int j = rem >> 6, l = rem & 63;
    const float* pp = g_part + half*(4*NE*64);
    float s = pp[0*(NE*64)+j*64+l] + pp[1*(NE*64)+j*64+l]
            + pp[2*(NE*64)+j*64+l] + pp[3*(NE*64)+j*64+l];
    (half ? g_pd : g_pu)[j*64 + l] = s * (1.f/256.f);
  } else {
    int h = bid - 256;
    const float* sv = g_sv[svsel];
    float s = 0.f;
    for (int i = 0; i < 256; ++i) s += sv[(h*256 + i)*256 + t];
    (h ? g_sd : g_su)[t] = s * (1.f/256.f);
  }
}

// ---------------- generic s-channel matmul (layers / heads / orbitals) ----------------
// which: 0=layer0, 1..3=layer l, 4=head_u, 5=head_d, 6=orb_u, 7=orb_d
template<int PUK, int SVK, int MEANK>
__global__ __launch_bounds__(256) void k_smm(int which, const float* __restrict__ W,
                                             const float* __restrict__ Wb) {
  constexpr int MAINK = 2*PUK + SVK;
  __shared__ __align__(16) float wsl[MAINK*32];
  __shared__ float insl[32*(MAINK+1)];
  __shared__ float biasv[32];
  __shared__ float bred[256];
  const float *pu_p=nullptr, *pd_p=nullptr, *sv_p=nullptr, *su_p=nullptr, *sd_p=nullptr;
  const float *res_p=nullptr, *rs_p=nullptr;
  float* out_p = nullptr;
  int row0 = 0, dotanh = 1;
  switch (which) {
    case 0: pu_p=g_pu4; pd_p=g_pd4; su_p=g_su0; sd_p=g_sd0; sv_p=g_sv0; out_p=g_sv[0]; break;
    case 1: case 2: case 3:
      pu_p=g_pu; pd_p=g_pd; su_p=g_su; sd_p=g_sd;
      sv_p=g_sv[(which+1)&1]; res_p=sv_p; out_p=g_sv[which&1]; break;
    case 4: pu_p=g_pu; pd_p=g_pd; su_p=g_su; sd_p=g_sd; sv_p=g_sv[1]; out_p=g_hu; break;
    case 5: pu_p=g_pu; pd_p=g_pd; su_p=g_su; sd_p=g_sd; sv_p=g_sv[1]; out_p=g_hd; row0=256; break;
    case 6: sv_p=g_hu; out_p=g_orbu; rs_p=g_f;       dotanh=0; break;
    default: sv_p=g_hd; out_p=g_orbd; rs_p=g_f+256;  dotanh=0; break;
  }
  int t = threadIdx.x;
  int rg = blockIdx.x, cg = blockIdx.y;
  int col0 = cg * 32;
  for (int idx = t; idx < MAINK*32; idx += 256) {
    int c = idx >> 5, cl = idx & 31;
    wsl[idx] = W[(2*MEANK + c)*256 + col0 + cl];
  }
  for (int rr = 0; rr < 32; ++rr) {
    int row = row0 + rg*32 + rr;
    for (int c = t; c < MAINK; c += 256) {
      float v;
      if (c < PUK) v = pu_p[row*PUK + c];
      else if (c < 2*PUK) v = pd_p[row*PUK + (c - PUK)];
      else v = sv_p[row*SVK + (c - 2*PUK)];
      insl[rr*(MAINK+1) + c] = v;
    }
  }
  {
    int pcol = t & 31, ps = t >> 5;
    float bacc = 0.f;
    if (MEANK > 0) {
      for (int c = ps; c < MEANK; c += 8)
        bacc += su_p[c]*W[c*256 + col0 + pcol] + sd_p[c]*W[(MEANK + c)*256 + col0 + pcol];
    }
    bred[ps*32 + pcol] = bacc;
  }
  __syncthreads();
  if (t < 32) {
    float s = Wb[col0 + t];
    #pragma unroll
    for (int p8 = 0; p8 < 8; ++p8) s += bred[p8*32 + t];
    biasv[t] = s;
  }
  __syncthreads();
  int c4 = t & 7, rl = t >> 3;
  float a0 = biasv[4*c4], a1 = biasv[4*c4+1], a2 = biasv[4*c4+2], a3 = biasv[4*c4+3];
  const float* inrow = &insl[rl*(MAINK+1)];
  for (int c = 0; c < MAINK; ++c) {
    float iv = inrow[c];
    float4 wv = *(const float4*)&wsl[c*32 + 4*c4];
    a0 += iv*wv.x; a1 += iv*wv.y; a2 += iv*wv.z; a3 += iv*wv.w;
  }
  int rowA = rg*32 + rl;
  int col = col0 + 4*c4;
  if (dotanh) { a0=tanh_fast(a0); a1=tanh_fast(a1); a2=tanh_fast(a2); a3=tanh_fast(a3); }
  if (res_p) {
    float4 rv = *(const float4*)&res_p[rowA*256 + col];
    a0 += rv.x; a1 += rv.y; a2 += rv.z; a3 += rv.w;
  }
  if (rs_p) { float fsc = rs_p[rowA]; a0*=fsc; a1*=fsc; a2*=fsc; a3*=fsc; }
  float4 ov; ov.x=a0; ov.y=a1; ov.z=a2; ov.w=a3;
  *(float4*)&out_p[rowA*256 + col] = ov;
}

// ---------------- register-resident LU, 2-D tiles (v4 — best measured: 307us) ----------------
// R5 lesson: v5's blocked variant spilled (VGPR 128 + 912KB scratch writes) via
// switch-heavy owner paths with too many live float4 temps. Reverted to v4 verbatim.
#define REP8(M) M(0) M(1) M(2) M(3) M(4) M(5) M(6) M(7)

__global__ __launch_bounds__(512, 2) void k_lu() {
  __shared__ __align__(16) float colbuf[256];
  __shared__ __align__(16) float prowbuf[16*68];     // group c at word 68c (padded)
  const float* A = (blockIdx.x == 0) ? g_orbu : g_orbd;
  int t = threadIdx.x;
  int tile_r = t >> 4;        // 0..31 -> rows 8*tile_r .. +7
  int tile_c = t & 15;        // 0..15 -> cols 16*tile_c .. +15
  int lane = t & 63;
  int br = tile_r * 8;
  int pb = tile_c * 68;
  const float4* Ap = (const float4*)(A + (tile_r*8)*256 + tile_c*16);
  // row stride = 64 float4
#define DECLROW(R) float4 M##R##_0 = Ap[R*64+0], M##R##_1 = Ap[R*64+1], \
                          M##R##_2 = Ap[R*64+2], M##R##_3 = Ap[R*64+3];
  REP8(DECLROW)
#undef DECLROW
  unsigned um = 0;            // used-mask for candidate rows 4*lane..4*lane+3
  if (tile_c == 0) {
#define INIT0(R) colbuf[br+R] = M##R##_0.x;
    REP8(INIT0)
#undef INIT0
  }
  __syncthreads();
  float logsum = 0.f;
  for (int k = 0; k < 256; ++k) {
    // ---- phase S: pivot search on colbuf (holds column k) ----
    float4 cv = *(const float4*)&colbuf[4*lane];
    unsigned b0 = (um & 1u) ? 0u : ((__float_as_uint(fabsf(cv.x)) & 0xFFFFFF00u) | (unsigned)(4*lane+0));
    unsigned b1 = (um & 2u) ? 0u : ((__float_as_uint(fabsf(cv.y)) & 0xFFFFFF00u) | (unsigned)(4*lane+1));
    unsigned b2 = (um & 4u) ? 0u : ((__float_as_uint(fabsf(cv.z)) & 0xFFFFFF00u) | (unsigned)(4*lane+2));
    unsigned b3 = (um & 8u) ? 0u : ((__float_as_uint(fabsf(cv.w)) & 0xFFFFFF00u) | (unsigned)(4*lane+3));
    unsigned bb = max(max(b0,b1), max(b2,b3));
    #pragma unroll
    for (int m = 1; m < 64; m <<= 1) {
      unsigned ob = __shfl_xor(bb, m);
      bb = ob > bb ? ob : bb;
    }
    int p = (int)(bb & 255u);
    float piv = colbuf[p];
    logsum += logf(fabsf(piv));
    if ((p >> 2) == lane) um |= 1u << (p & 3);
    if (k == 255) break;
    float rp = 1.0f / piv;
    float4 ca = *(const float4*)&colbuf[br];
    float4 cb = *(const float4*)&colbuf[br+4];
    float m0 = ca.x*rp, m1 = ca.y*rp, m2 = ca.z*rp, m3 = ca.w*rp;
    float m4 = cb.x*rp, m5 = cb.y*rp, m6 = cb.z*rp, m7 = cb.w*rp;
    // pivot-row owners publish their 16-col slice (uniform switch on p&7)
    if (tile_r == (p >> 3)) {
      switch (p & 7) {
#define PUBC(R) case R: *(float4*)&prowbuf[pb+0] = M##R##_0; *(float4*)&prowbuf[pb+4] = M##R##_1; \
                        *(float4*)&prowbuf[pb+8] = M##R##_2; *(float4*)&prowbuf[pb+12] = M##R##_3; break;
        REP8(PUBC)
#undef PUBC
      }
    }
    __syncthreads();
    // ---- phase U: rank-1 update + extract column k+1 ----
    float4 P0 = *(const float4*)&prowbuf[pb+0];
    float4 P1 = *(const float4*)&prowbuf[pb+4];
    float4 P2 = *(const float4*)&prowbuf[pb+8];
    float4 P3 = *(const float4*)&prowbuf[pb+12];
#define UPD(R) { float mr = m##R; \
  M##R##_0.x -= mr*P0.x; M##R##_0.y -= mr*P0.y; M##R##_0.z -= mr*P0.z; M##R##_0.w -= mr*P0.w; \
  M##R##_1.x -= mr*P1.x; M##R##_1.y -= mr*P1.y; M##R##_1.z -= mr*P1.z; M##R##_1.w -= mr*P1.w; \
  M##R##_2.x -= mr*P2.x; M##R##_2.y -= mr*P2.y; M##R##_2.z -= mr*P2.z; M##R##_2.w -= mr*P2.w; \
  M##R##_3.x -= mr*P3.x; M##R##_3.y -= mr*P3.y; M##R##_3.z -= mr*P3.z; M##R##_3.w -= mr*P3.w; }
    REP8(UPD)
#undef UPD
    int kn = k + 1;
    if (tile_c == (kn >> 4)) {
      switch (kn & 15) {
#define EXTC(I, G, C) case I: { colbuf[br+0]=M0_##G.C; colbuf[br+1]=M1_##G.C; \
  colbuf[br+2]=M2_##G.C; colbuf[br+3]=M3_##G.C; colbuf[br+4]=M4_##G.C; \
  colbuf[br+5]=M5_##G.C; colbuf[br+6]=M6_##G.C; colbuf[br+7]=M7_##G.C; } break;
        EXTC(0,0,x) EXTC(1,0,y) EXTC(2,0,z) EXTC(3,0,w)
        EXTC(4,1,x) EXTC(5,1,y) EXTC(6,1,z) EXTC(7,1,w)
        EXTC(8,2,x) EXTC(9,2,y) EXTC(10,2,z) EXTC(11,2,w)
        EXTC(12,3,x) EXTC(13,3,y) EXTC(14,3,z) EXTC(15,3,w)
#undef EXTC
      }
    }
    __syncthreads();
  }
  if (t == 0) g_logs[blockIdx.x] = logsum;
}

__global__ void k_final(float* out) { out[0] = g_logs[0] + g_logs[1]; }

// ---------------- launch ----------------
extern "C" void kernel_launch(void* const* d_in, const int* in_sizes, int n_in,
                              void* d_out, int out_size, void* d_ws, size_t ws_size,
                              hipStream_t stream) {
  const float* r     = (const float*)d_in[0];
  const float* a     = (const float*)d_in[1];
  const float* V0_W  = (const float*)d_in[2];
  const float* V0_b  = (const float*)d_in[3];
  const float* Vr_W  = (const float*)d_in[4];
  const float* Vr_b  = (const float*)d_in[5];
  const float* W0_W  = (const float*)d_in[6];
  const float* W0_b  = (const float*)d_in[7];
  const float* Wr_W  = (const float*)d_in[8];
  const float* Wr_b  = (const float*)d_in[9];
  const float* Vhu_W = (const float*)d_in[10];
  const float* Vhu_b = (const float*)d_in[11];
  const float* Vhd_W = (const float*)d_in[12];
  const float* Vhd_b = (const float*)d_in[13];
  const float* wu_W  = (const float*)d_in[14];
  const float* wu_b  = (const float*)d_in[15];
  const float* wd_W  = (const float*)d_in[16];
  const float* wd_b  = (const float*)d_in[17];
  float* out = (float*)d_out;

  k_geom<<<1, 512, 0, stream>>>(r, a);
  k_pmean0<<<512, 256, 0, stream>>>(r);

  // layer 0
  k_smm<4,64,64><<<dim3(16,8), 256, 0, stream>>>(0, V0_W, V0_b);
  k_pup<0><<<1024, 256, 0, stream>>>(W0_W, W0_b, r, 0, 0);
  k_reduce<<<258, 256, 0, stream>>>(0);
  // layer 1
  k_smm<64,256,256><<<dim3(16,8), 256, 0, stream>>>(1, Vr_W + 0*896*256, Vr_b + 0);
  k_pup<1><<<1024, 256, 0, stream>>>(Wr_W + 0*4096, Wr_b + 0, r, 0, 1);
  k_reduce<<<258, 256, 0, stream>>>(1);
  // layer 2
  k_smm<64,256,256><<<dim3(16,8), 256, 0, stream>>>(2, Vr_W + 1*896*256, Vr_b + 256);
  k_pup<1><<<1024, 256, 0, stream>>>(Wr_W + 1*4096, Wr_b + 64, r, 1, 0);
  k_reduce<<<258, 256, 0, stream>>>(0);
  // layer 3 (p4 not stored; only its means)
  k_smm<64,256,256><<<dim3(16,8), 256, 0, stream>>>(3, Vr_W + 2*896*256, Vr_b + 512);
  k_pup<2><<<1024, 256, 0, stream>>>(Wr_W + 2*4096, Wr_b + 128, r, 0, 0);
  k_reduce<<<258, 256, 0, stream>>>(1);
  // heads
  k_smm<64,256,256><<<dim3(8,8), 256, 0, stream>>>(4, Vhu_W, Vhu_b);
  k_smm<64,256,256><<<dim3(8,8), 256, 0, stream>>>(5, Vhd_W, Vhd_b);
  // orbitals
  k_smm<0,256,0><<<dim3(8,8), 256, 0, stream>>>(6, wu_W, wu_b);
  k_smm<0,256,0><<<dim3(8,8), 256, 0, stream>>>(7, wd_W, wd_b);
  // log|det| x2 and combine
  k_lu<<<2, 512, 0, stream>>>();
  k_final<<<1, 1, 0, stream>>>(out);
}

// Round 7
// 867.397 us; speedup vs baseline: 2.1412x; 1.1865x over previous
//
#include <hip/hip_runtime.h>
#include <hip/hip_bf16.h>

#define NE 512

// ---------------- static device buffers (avoid d_ws dependence) ----------------
__device__ __align__(16) float g_p[2][NE*NE*64];     // ping-pong pair features (67MB each)
__device__ __align__(16) float g_sv0[NE*64];
__device__ __align__(16) float g_sv[2][NE*256];
__device__ __align__(16) float g_pu4[NE*4];
__device__ __align__(16) float g_pd4[NE*4];
__device__ __align__(16) float g_pu[NE*64];
__device__ __align__(16) float g_pd[NE*64];
__device__ __align__(16) float g_su0[64];
__device__ __align__(16) float g_sd0[64];
__device__ __align__(16) float g_su[256];
__device__ __align__(16) float g_sd[256];
__device__ __align__(16) float g_part[8*NE*64];      // per-(j,chunk) partial means of p
__device__ __align__(16) float g_f[NE];              // sum_a exp(-|r_i - a|)
__device__ __align__(16) float g_hu[256*256];
__device__ __align__(16) float g_hd[256*256];
__device__ __align__(16) float g_orbu[256*256];
__device__ __align__(16) float g_orbd[256*256];
__device__ float g_logs[2];

__device__ __forceinline__ float tanh_fast(float x) {
  float e = __expf(2.f * x);
  return 1.f - 2.f / (e + 1.f);
}

// ---------------- K0: geometry -> s_v0, f, su0/sd0 ----------------
__global__ __launch_bounds__(512) void k_geom(const float* __restrict__ r,
                                              const float* __restrict__ a) {
  int e = threadIdx.x;
  float rx = r[3*e], ry = r[3*e+1], rz = r[3*e+2];
  float facc = 0.f;
  #pragma unroll
  for (int at = 0; at < 16; ++at) {
    float dx = rx - a[3*at], dy = ry - a[3*at+1], dz = rz - a[3*at+2];
    float len = sqrtf(dx*dx + dy*dy + dz*dz);
    g_sv0[e*64 + 4*at + 0] = dx;
    g_sv0[e*64 + 4*at + 1] = dy;
    g_sv0[e*64 + 4*at + 2] = dz;
    g_sv0[e*64 + 4*at + 3] = len;
    facc += expf(-len);
  }
  g_f[e] = facc;
  __syncthreads();            // global writes visible within block after barrier
  if (e < 128) {
    int h = e >> 6, c = e & 63;
    float s = 0.f;
    for (int i = 0; i < 256; ++i) s += g_sv0[(h*256 + i)*64 + c];
    (h ? g_sd0 : g_su0)[c] = s * (1.f/256.f);
  }
}

// ---------------- K0b: means of p0 (4-dim geometry pairs) ----------------
__global__ __launch_bounds__(256) void k_pmean0(const float* __restrict__ r) {
  int j = blockIdx.x, t = threadIdx.x;
  float rjx = r[3*j], rjy = r[3*j+1], rjz = r[3*j+2];
  __shared__ float red[4][4];
  for (int h = 0; h < 2; ++h) {
    int i = h*256 + t;
    float dx = rjx - r[3*i], dy = rjy - r[3*i+1], dz = rjz - r[3*i+2];
    float ee = (i == j) ? 1.f : 0.f;
    float ex = dx+ee, ey = dy+ee, ez = dz+ee;
    float len = sqrtf(ex*ex + ey*ey + ez*ez);
    float v0 = dx, v1 = dy, v2 = dz, v3 = len;
    #pragma unroll
    for (int m = 1; m < 64; m <<= 1) {
      v0 += __shfl_xor(v0, m); v1 += __shfl_xor(v1, m);
      v2 += __shfl_xor(v2, m); v3 += __shfl_xor(v3, m);
    }
    if ((t & 63) == 0) {
      int wv = t >> 6;
      red[wv][0]=v0; red[wv][1]=v1; red[wv][2]=v2; red[wv][3]=v3;
    }
    __syncthreads();
    if (t == 0) {
      float* dst = h ? g_pd4 : g_pu4;
      #pragma unroll
      for (int c = 0; c < 4; ++c)
        dst[j*4 + c] = (red[0][c]+red[1][c]+red[2][c]+red[3][c]) * (1.f/256.f);
    }
    __syncthreads();
  }
}

// ---------------- p-channel update. MODE 0: from geometry; 1: load+store; 2: load only ----
// R6 lesson: s_load broadcast serializes (SMEM lgkmcnt is out-of-order -> full drain
// per row). R7: v_readlane broadcast — the dot product runs entirely on the VALU:
// 64x {v_readlane s_k, x, k ; v_fmac acc, s_k, wcol[k]} per row, fully unrolled with
// compile-time lane indices. No LDS, no SMEM; 64 independent pairs give ILP.
template<int MODE>
__global__ __launch_bounds__(256) void k_pup(const float* __restrict__ W,
                                             const float* __restrict__ Wb,
                                             const float* __restrict__ r,
                                             int src, int dst) {
  int t = threadIdx.x, lane = t & 63, wv = t >> 6;
  int gw = blockIdx.x*4 + wv;          // 0..4095
  int j = gw >> 3, chunk = gw & 7;
  int i0 = chunk * 64;
  float macc = 0.f;
  if (MODE == 0) {
    float w0 = W[lane], w1 = W[64+lane], w2 = W[128+lane], w3 = W[192+lane];
    float bb = Wb[lane];
    float rjx = r[3*j], rjy = r[3*j+1], rjz = r[3*j+2];
    float* pout = g_p[0];
    for (int ii = 0; ii < 64; ++ii) {
      int i = i0 + ii;
      float dx = rjx - r[3*i], dy = rjy - r[3*i+1], dz = rjz - r[3*i+2];
      float ee = (i == j) ? 1.f : 0.f;
      float ex = dx+ee, ey = dy+ee, ez = dz+ee;
      float len = sqrtf(ex*ex + ey*ey + ez*ez);
      float y = tanh_fast(bb + dx*w0 + dy*w1 + dz*w2 + len*w3);
      pout[(i*NE + j)*64 + lane] = y;
      macc += y;
    }
  } else {
    const float* pin = g_p[src];
    float* pout = g_p[dst];
    float wcol[64];
    #pragma unroll
    for (int k = 0; k < 64; ++k) wcol[k] = W[k*64 + lane];
    float bb = Wb[lane];
    for (int ii = 0; ii < 64; ++ii) {
      int i = i0 + ii;
      int base = (i*NE + j)*64;
      float x = pin[base + lane];
      float acc = bb;
      unsigned xu = __float_as_uint(x);
      #pragma unroll
      for (int k = 0; k < 64; ++k) {
        float xk = __uint_as_float(__builtin_amdgcn_readlane(xu, k));
        acc = fmaf(xk, wcol[k], acc);
      }
      float y = tanh_fast(acc) + x;        // residual (layers >= 1)
      if (MODE == 1) pout[base + lane] = y;
      macc += y;
    }
  }
  g_part[chunk*(NE*64) + j*64 + lane] = macc;
}

// ---------------- finalize p-means + s-means ----------------
__global__ __launch_bounds__(256) void k_reduce(int svsel) {
  int bid = blockIdx.x, t = threadIdx.x;
  if (bid < 256) {
    int idx = bid*256 + t;
    int half = idx >> 15, rem = idx & 32767;
    int j = rem >> 6, l = rem & 63;
    const float* pp = g_part + half*(4*NE*64);
    float s = pp[0*(NE*64)+j*64+l] + pp[1*(NE*64)+j*64+l]
            + pp[2*(NE*64)+j*64+l] + pp[3*(NE*64)+j*64+l];
    (half ? g_pd : g_pu)[j*64 + l] = s * (1.f/256.f);
  } else {
    int h = bid - 256;
    const float* sv = g_sv[svsel];
    float s = 0.f;
    for (int i = 0; i < 256; ++i) s += sv[(h*256 + i)*256 + t];
    (h ? g_sd : g_su)[t] = s * (1.f/256.f);
  }
}

// ---------------- generic s-channel matmul (layers / heads / orbitals) ----------------
// which: 0=layer0, 1..3=layer l, 4=head_u, 5=head_d, 6=orb_u, 7=orb_d
template<int PUK, int SVK, int MEANK>
__global__ __launch_bounds__(256) void k_smm(int which, const float* __restrict__ W,
                                             const float* __restrict__ Wb) {
  constexpr int MAINK = 2*PUK + SVK;
  __shared__ __align__(16) float wsl[MAINK*32];
  __shared__ float insl[32*(MAINK+1)];
  __shared__ float biasv[32];
  __shared__ float bred[256];
  const float *pu_p=nullptr, *pd_p=nullptr, *sv_p=nullptr, *su_p=nullptr, *sd_p=nullptr;
  const float *res_p=nullptr, *rs_p=nullptr;
  float* out_p = nullptr;
  int row0 = 0, dotanh = 1;
  switch (which) {
    case 0: pu_p=g_pu4; pd_p=g_pd4; su_p=g_su0; sd_p=g_sd0; sv_p=g_sv0; out_p=g_sv[0]; break;
    case 1: case 2: case 3:
      pu_p=g_pu; pd_p=g_pd; su_p=g_su; sd_p=g_sd;
      sv_p=g_sv[(which+1)&1]; res_p=sv_p; out_p=g_sv[which&1]; break;
    case 4: pu_p=g_pu; pd_p=g_pd; su_p=g_su; sd_p=g_sd; sv_p=g_sv[1]; out_p=g_hu; break;
    case 5: pu_p=g_pu; pd_p=g_pd; su_p=g_su; sd_p=g_sd; sv_p=g_sv[1]; out_p=g_hd; row0=256; break;
    case 6: sv_p=g_hu; out_p=g_orbu; rs_p=g_f;       dotanh=0; break;
    default: sv_p=g_hd; out_p=g_orbd; rs_p=g_f+256;  dotanh=0; break;
  }
  int t = threadIdx.x;
  int rg = blockIdx.x, cg = blockIdx.y;
  int col0 = cg * 32;
  for (int idx = t; idx < MAINK*32; idx += 256) {
    int c = idx >> 5, cl = idx & 31;
    wsl[idx] = W[(2*MEANK + c)*256 + col0 + cl];
  }
  for (int rr = 0; rr < 32; ++rr) {
    int row = row0 + rg*32 + rr;
    for (int c = t; c < MAINK; c += 256) {
      float v;
      if (c < PUK) v = pu_p[row*PUK + c];
      else if (c < 2*PUK) v = pd_p[row*PUK + (c - PUK)];
      else v = sv_p[row*SVK + (c - 2*PUK)];
      insl[rr*(MAINK+1) + c] = v;
    }
  }
  {
    int pcol = t & 31, ps = t >> 5;
    float bacc = 0.f;
    if (MEANK > 0) {
      for (int c = ps; c < MEANK; c += 8)
        bacc += su_p[c]*W[c*256 + col0 + pcol] + sd_p[c]*W[(MEANK + c)*256 + col0 + pcol];
    }
    bred[ps*32 + pcol] = bacc;
  }
  __syncthreads();
  if (t < 32) {
    float s = Wb[col0 + t];
    #pragma unroll
    for (int p8 = 0; p8 < 8; ++p8) s += bred[p8*32 + t];
    biasv[t] = s;
  }
  __syncthreads();
  int c4 = t & 7, rl = t >> 3;
  float a0 = biasv[4*c4], a1 = biasv[4*c4+1], a2 = biasv[4*c4+2], a3 = biasv[4*c4+3];
  const float* inrow = &insl[rl*(MAINK+1)];
  for (int c = 0; c < MAINK; ++c) {
    float iv = inrow[c];
    float4 wv = *(const float4*)&wsl[c*32 + 4*c4];
    a0 += iv*wv.x; a1 += iv*wv.y; a2 += iv*wv.z; a3 += iv*wv.w;
  }
  int rowA = rg*32 + rl;
  int col = col0 + 4*c4;
  if (dotanh) { a0=tanh_fast(a0); a1=tanh_fast(a1); a2=tanh_fast(a2); a3=tanh_fast(a3); }
  if (res_p) {
    float4 rv = *(const float4*)&res_p[rowA*256 + col];
    a0 += rv.x; a1 += rv.y; a2 += rv.z; a3 += rv.w;
  }
  if (rs_p) { float fsc = rs_p[rowA]; a0*=fsc; a1*=fsc; a2*=fsc; a3*=fsc; }
  float4 ov; ov.x=a0; ov.y=a1; ov.z=a2; ov.w=a3;
  *(float4*)&out_p[rowA*256 + col] = ov;
}

// ---------------- register-resident LU, 2-D tiles (v4 — best measured: 305us) ----------------
#define REP8(M) M(0) M(1) M(2) M(3) M(4) M(5) M(6) M(7)

__global__ __launch_bounds__(512, 2) void k_lu() {
  __shared__ __align__(16) float colbuf[256];
  __shared__ __align__(16) float prowbuf[16*68];     // group c at word 68c (padded)
  const float* A = (blockIdx.x == 0) ? g_orbu : g_orbd;
  int t = threadIdx.x;
  int tile_r = t >> 4;        // 0..31 -> rows 8*tile_r .. +7
  int tile_c = t & 15;        // 0..15 -> cols 16*tile_c .. +15
  int lane = t & 63;
  int br = tile_r * 8;
  int pb = tile_c * 68;
  const float4* Ap = (const float4*)(A + (tile_r*8)*256 + tile_c*16);
  // row stride = 64 float4
#define DECLROW(R) float4 M##R##_0 = Ap[R*64+0], M##R##_1 = Ap[R*64+1], \
                          M##R##_2 = Ap[R*64+2], M##R##_3 = Ap[R*64+3];
  REP8(DECLROW)
#undef DECLROW
  unsigned um = 0;            // used-mask for candidate rows 4*lane..4*lane+3
  if (tile_c == 0) {
#define INIT0(R) colbuf[br+R] = M##R##_0.x;
    REP8(INIT0)
#undef INIT0
  }
  __syncthreads();
  float logsum = 0.f;
  for (int k = 0; k < 256; ++k) {
    // ---- phase S: pivot search on colbuf (holds column k) ----
    float4 cv = *(const float4*)&colbuf[4*lane];
    unsigned b0 = (um & 1u) ? 0u : ((__float_as_uint(fabsf(cv.x)) & 0xFFFFFF00u) | (unsigned)(4*lane+0));
    unsigned b1 = (um & 2u) ? 0u : ((__float_as_uint(fabsf(cv.y)) & 0xFFFFFF00u) | (unsigned)(4*lane+1));
    unsigned b2 = (um & 4u) ? 0u : ((__float_as_uint(fabsf(cv.z)) & 0xFFFFFF00u) | (unsigned)(4*lane+2));
    unsigned b3 = (um & 8u) ? 0u : ((__float_as_uint(fabsf(cv.w)) & 0xFFFFFF00u) | (unsigned)(4*lane+3));
    unsigned bb = max(max(b0,b1), max(b2,b3));
    #pragma unroll
    for (int m = 1; m < 64; m <<= 1) {
      unsigned ob = __shfl_xor(bb, m);
      bb = ob > bb ? ob : bb;
    }
    int p = (int)(bb & 255u);
    float piv = colbuf[p];
    logsum += logf(fabsf(piv));
    if ((p >> 2) == lane) um |= 1u << (p & 3);
    if (k == 255) break;
    float rp = 1.0f / piv;
    float4 ca = *(const float4*)&colbuf[br];
    float4 cb = *(const float4*)&colbuf[br+4];
    float m0 = ca.x*rp, m1 = ca.y*rp, m2 = ca.z*rp, m3 = ca.w*rp;
    float m4 = cb.x*rp, m5 = cb.y*rp, m6 = cb.z*rp, m7 = cb.w*rp;
    // pivot-row owners publish their 16-col slice (uniform switch on p&7)
    if (tile_r == (p >> 3)) {
      switch (p & 7) {
#define PUBC(R) case R: *(float4*)&prowbuf[pb+0] = M##R##_0; *(float4*)&prowbuf[pb+4] = M##R##_1; \
                        *(float4*)&prowbuf[pb+8] = M##R##_2; *(float4*)&prowbuf[pb+12] = M##R##_3; break;
        REP8(PUBC)
#undef PUBC
      }
    }
    __syncthreads();
    // ---- phase U: rank-1 update + extract column k+1 ----
    float4 P0 = *(const float4*)&prowbuf[pb+0];
    float4 P1 = *(const float4*)&prowbuf[pb+4];
    float4 P2 = *(const float4*)&prowbuf[pb+8];
    float4 P3 = *(const float4*)&prowbuf[pb+12];
#define UPD(R) { float mr = m##R; \
  M##R##_0.x -= mr*P0.x; M##R##_0.y -= mr*P0.y; M##R##_0.z -= mr*P0.z; M##R##_0.w -= mr*P0.w; \
  M##R##_1.x -= mr*P1.x; M##R##_1.y -= mr*P1.y; M##R##_1.z -= mr*P1.z; M##R##_1.w -= mr*P1.w; \
  M##R##_2.x -= mr*P2.x; M##R##_2.y -= mr*P2.y; M##R##_2.z -= mr*P2.z; M##R##_2.w -= mr*P2.w; \
  M##R##_3.x -= mr*P3.x; M##R##_3.y -= mr*P3.y; M##R##_3.z -= mr*P3.z; M##R##_3.w -= mr*P3.w; }
    REP8(UPD)
#undef UPD
    int kn = k + 1;
    if (tile_c == (kn >> 4)) {
      switch (kn & 15) {
#define EXTC(I, G, C) case I: { colbuf[br+0]=M0_##G.C; colbuf[br+1]=M1_##G.C; \
  colbuf[br+2]=M2_##G.C; colbuf[br+3]=M3_##G.C; colbuf[br+4]=M4_##G.C; \
  colbuf[br+5]=M5_##G.C; colbuf[br+6]=M6_##G.C; colbuf[br+7]=M7_##G.C; } break;
        EXTC(0,0,x) EXTC(1,0,y) EXTC(2,0,z) EXTC(3,0,w)
        EXTC(4,1,x) EXTC(5,1,y) EXTC(6,1,z) EXTC(7,1,w)
        EXTC(8,2,x) EXTC(9,2,y) EXTC(10,2,z) EXTC(11,2,w)
        EXTC(12,3,x) EXTC(13,3,y) EXTC(14,3,z) EXTC(15,3,w)
#undef EXTC
      }
    }
    __syncthreads();
  }
  if (t == 0) g_logs[blockIdx.x] = logsum;
}

__global__ void k_final(float* out) { out[0] = g_logs[0] + g_logs[1]; }

// ---------------- launch ----------------
extern "C" void kernel_launch(void* const* d_in, const int* in_sizes, int n_in,
                              void* d_out, int out_size, void* d_ws, size_t ws_size,
                              hipStream_t stream) {
  const float* r     = (const float*)d_in[0];
  const float* a     = (const float*)d_in[1];
  const float* V0_W  = (const float*)d_in[2];
  const float* V0_b  = (const float*)d_in[3];
  const float* Vr_W  = (const float*)d_in[4];
  const float* Vr_b  = (const float*)d_in[5];
  const float* W0_W  = (const float*)d_in[6];
  const float* W0_b  = (const float*)d_in[7];
  const float* Wr_W  = (const float*)d_in[8];
  const float* Wr_b  = (const float*)d_in[9];
  const float* Vhu_W = (const float*)d_in[10];
  const float* Vhu_b = (const float*)d_in[11];
  const float* Vhd_W = (const float*)d_in[12];
  const float* Vhd_b = (const float*)d_in[13];
  const float* wu_W  = (const float*)d_in[14];
  const float* wu_b  = (const float*)d_in[15];
  const float* wd_W  = (const float*)d_in[16];
  const float* wd_b  = (const float*)d_in[17];
  float* out = (float*)d_out;

  k_geom<<<1, 512, 0, stream>>>(r, a);
  k_pmean0<<<512, 256, 0, stream>>>(r);

  // layer 0
  k_smm<4,64,64><<<dim3(16,8), 256, 0, stream>>>(0, V0_W, V0_b);
  k_pup<0><<<1024, 256, 0, stream>>>(W0_W, W0_b, r, 0, 0);
  k_reduce<<<258, 256, 0, stream>>>(0);
  // layer 1
  k_smm<64,256,256><<<dim3(16,8), 256, 0, stream>>>(1, Vr_W + 0*896*256, Vr_b + 0);
  k_pup<1><<<1024, 256, 0, stream>>>(Wr_W + 0*4096, Wr_b + 0, r, 0, 1);
  k_reduce<<<258, 256, 0, stream>>>(1);
  // layer 2
  k_smm<64,256,256><<<dim3(16,8), 256, 0, stream>>>(2, Vr_W + 1*896*256, Vr_b + 256);
  k_pup<1><<<1024, 256, 0, stream>>>(Wr_W + 1*4096, Wr_b + 64, r, 1, 0);
  k_reduce<<<258, 256, 0, stream>>>(0);
  // layer 3 (p4 not stored; only its means)
  k_smm<64,256,256><<<dim3(16,8), 256, 0, stream>>>(3, Vr_W + 2*896*256, Vr_b + 512);
  k_pup<2><<<1024, 256, 0, stream>>>(Wr_W + 2*4096, Wr_b + 128, r, 0, 0);
  k_reduce<<<258, 256, 0, stream>>>(1);
  // heads
  k_smm<64,256,256><<<dim3(8,8), 256, 0, stream>>>(4, Vhu_W, Vhu_b);
  k_smm<64,256,256><<<dim3(8,8), 256, 0, stream>>>(5, Vhd_W, Vhd_b);
  // orbitals
  k_smm<0,256,0><<<dim3(8,8), 256, 0, stream>>>(6, wu_W, wu_b);
  k_smm<0,256,0><<<dim3(8,8), 256, 0, stream>>>(7, wd_W, wd_b);
  // log|det| x2 and combine
  k_lu<<<2, 512, 0, stream>>>();
  k_final<<<1, 1, 0, stream>>>(out);
}

// Round 8
// 781.652 us; speedup vs baseline: 2.3761x; 1.1097x over previous
//
#include <hip/hip_runtime.h>
#include <hip/hip_bf16.h>

#define NE 512

// ---------------- static device buffers (avoid d_ws dependence) ----------------
__device__ __align__(16) float g_p[2][NE*NE*64];     // ping-pong pair features (67MB each)
__device__ __align__(16) float g_sv0[NE*64];
__device__ __align__(16) float g_sv[2][NE*256];
__device__ __align__(16) float g_pu4[NE*4];
__device__ __align__(16) float g_pd4[NE*4];
__device__ __align__(16) float g_pu[NE*64];
__device__ __align__(16) float g_pd[NE*64];
__device__ __align__(16) float g_su0[64];
__device__ __align__(16) float g_sd0[64];
__device__ __align__(16) float g_su[256];
__device__ __align__(16) float g_sd[256];
__device__ __align__(16) float g_part[8*NE*64];      // per-(j,chunk) partial means of p
__device__ __align__(16) float g_f[NE];              // sum_a exp(-|r_i - a|)
__device__ __align__(16) float g_hu[256*256];
__device__ __align__(16) float g_hd[256*256];
__device__ __align__(16) float g_orbu[256*256];
__device__ __align__(16) float g_orbd[256*256];
__device__ float g_logs[2];

__device__ __forceinline__ float tanh_fast(float x) {
  float e = __expf(2.f * x);
  return 1.f - 2.f / (e + 1.f);
}

// ---------------- K0: geometry -> s_v0, f, su0/sd0 ----------------
__global__ __launch_bounds__(512) void k_geom(const float* __restrict__ r,
                                              const float* __restrict__ a) {
  int e = threadIdx.x;
  float rx = r[3*e], ry = r[3*e+1], rz = r[3*e+2];
  float facc = 0.f;
  #pragma unroll
  for (int at = 0; at < 16; ++at) {
    float dx = rx - a[3*at], dy = ry - a[3*at+1], dz = rz - a[3*at+2];
    float len = sqrtf(dx*dx + dy*dy + dz*dz);
    g_sv0[e*64 + 4*at + 0] = dx;
    g_sv0[e*64 + 4*at + 1] = dy;
    g_sv0[e*64 + 4*at + 2] = dz;
    g_sv0[e*64 + 4*at + 3] = len;
    facc += expf(-len);
  }
  g_f[e] = facc;
  __syncthreads();            // global writes visible within block after barrier
  if (e < 128) {
    int h = e >> 6, c = e & 63;
    float s = 0.f;
    for (int i = 0; i < 256; ++i) s += g_sv0[(h*256 + i)*64 + c];
    (h ? g_sd0 : g_su0)[c] = s * (1.f/256.f);
  }
}

// ---------------- K0b: means of p0 (4-dim geometry pairs) ----------------
__global__ __launch_bounds__(256) void k_pmean0(const float* __restrict__ r) {
  int j = blockIdx.x, t = threadIdx.x;
  float rjx = r[3*j], rjy = r[3*j+1], rjz = r[3*j+2];
  __shared__ float red[4][4];
  for (int h = 0; h < 2; ++h) {
    int i = h*256 + t;
    float dx = rjx - r[3*i], dy = rjy - r[3*i+1], dz = rjz - r[3*i+2];
    float ee = (i == j) ? 1.f : 0.f;
    float ex = dx+ee, ey = dy+ee, ez = dz+ee;
    float len = sqrtf(ex*ex + ey*ey + ez*ez);
    float v0 = dx, v1 = dy, v2 = dz, v3 = len;
    #pragma unroll
    for (int m = 1; m < 64; m <<= 1) {
      v0 += __shfl_xor(v0, m); v1 += __shfl_xor(v1, m);
      v2 += __shfl_xor(v2, m); v3 += __shfl_xor(v3, m);
    }
    if ((t & 63) == 0) {
      int wv = t >> 6;
      red[wv][0]=v0; red[wv][1]=v1; red[wv][2]=v2; red[wv][3]=v3;
    }
    __syncthreads();
    if (t == 0) {
      float* dst = h ? g_pd4 : g_pu4;
      #pragma unroll
      for (int c = 0; c < 4; ++c)
        dst[j*4 + c] = (red[0][c]+red[1][c]+red[2][c]+red[3][c]) * (1.f/256.f);
    }
    __syncthreads();
  }
}

// ---------------- p-channel update. MODE 0: from geometry; 1: load+store; 2: load only ----
// R7 lesson: readlane-broadcast (562us tier) < LDS-broadcast (495us tier) — reverted
// to R4's psh wave-uniform ds_read_b128 broadcast (best measured).
template<int MODE>
__global__ __launch_bounds__(256) void k_pup(const float* __restrict__ W,
                                             const float* __restrict__ Wb,
                                             const float* __restrict__ r,
                                             int src, int dst) {
  __shared__ __align__(16) float psh[4][64];
  int t = threadIdx.x, lane = t & 63, wv = t >> 6;
  int gw = blockIdx.x*4 + wv;          // 0..4095
  int j = gw >> 3, chunk = gw & 7;
  int i0 = chunk * 64;
  float macc = 0.f;
  if (MODE == 0) {
    float w0 = W[lane], w1 = W[64+lane], w2 = W[128+lane], w3 = W[192+lane];
    float bb = Wb[lane];
    float rjx = r[3*j], rjy = r[3*j+1], rjz = r[3*j+2];
    float* pout = g_p[0];
    for (int ii = 0; ii < 64; ++ii) {
      int i = i0 + ii;
      float dx = rjx - r[3*i], dy = rjy - r[3*i+1], dz = rjz - r[3*i+2];
      float ee = (i == j) ? 1.f : 0.f;
      float ex = dx+ee, ey = dy+ee, ez = dz+ee;
      float len = sqrtf(ex*ex + ey*ey + ez*ez);
      float y = tanh_fast(bb + dx*w0 + dy*w1 + dz*w2 + len*w3);
      pout[(i*NE + j)*64 + lane] = y;
      macc += y;
    }
  } else {
    const float* pin = g_p[src];
    float* pout = g_p[dst];
    float wcol[64];
    #pragma unroll
    for (int k = 0; k < 64; ++k) wcol[k] = W[k*64 + lane];
    float bb = Wb[lane];
    for (int ii = 0; ii < 64; ++ii) {
      int i = i0 + ii;
      int base = (i*NE + j)*64;
      float x = pin[base + lane];
      psh[wv][lane] = x;
      float acc = bb;
      #pragma unroll
      for (int g = 0; g < 16; ++g) {
        float4 pv = *(const float4*)&psh[wv][4*g];   // wave-uniform broadcast reads
        acc += pv.x*wcol[4*g] + pv.y*wcol[4*g+1] + pv.z*wcol[4*g+2] + pv.w*wcol[4*g+3];
      }
      float y = tanh_fast(acc) + x;                  // residual (layers >= 1)
      if (MODE == 1) pout[base + lane] = y;
      macc += y;
    }
  }
  g_part[chunk*(NE*64) + j*64 + lane] = macc;
}

// ---------------- finalize p-means + s-means ----------------
__global__ __launch_bounds__(256) void k_reduce(int svsel) {
  int bid = blockIdx.x, t = threadIdx.x;
  if (bid < 256) {
    int idx = bid*256 + t;
    int half = idx >> 15, rem = idx & 32767;
    int j = rem >> 6, l = rem & 63;
    const float* pp = g_part + half*(4*NE*64);
    float s = pp[0*(NE*64)+j*64+l] + pp[1*(NE*64)+j*64+l]
            + pp[2*(NE*64)+j*64+l] + pp[3*(NE*64)+j*64+l];
    (half ? g_pd : g_pu)[j*64 + l] = s * (1.f/256.f);
  } else {
    int h = bid - 256;
    const float* sv = g_sv[svsel];
    float s = 0.f;
    for (int i = 0; i < 256; ++i) s += sv[(h*256 + i)*256 + t];
    (h ? g_sd : g_su)[t] = s * (1.f/256.f);
  }
}

// ---------------- generic s-channel matmul (layers / heads / orbitals) ----------------
// which: 0=layer0, 1..3=layer l, 4=head_u, 5=head_d, 6=orb_u, 7=orb_d
template<int PUK, int SVK, int MEANK>
__global__ __launch_bounds__(256) void k_smm(int which, const float* __restrict__ W,
                                             const float* __restrict__ Wb) {
  constexpr int MAINK = 2*PUK + SVK;
  __shared__ __align__(16) float wsl[MAINK*32];
  __shared__ float insl[32*(MAINK+1)];
  __shared__ float biasv[32];
  __shared__ float bred[256];
  const float *pu_p=nullptr, *pd_p=nullptr, *sv_p=nullptr, *su_p=nullptr, *sd_p=nullptr;
  const float *res_p=nullptr, *rs_p=nullptr;
  float* out_p = nullptr;
  int row0 = 0, dotanh = 1;
  switch (which) {
    case 0: pu_p=g_pu4; pd_p=g_pd4; su_p=g_su0; sd_p=g_sd0; sv_p=g_sv0; out_p=g_sv[0]; break;
    case 1: case 2: case 3:
      pu_p=g_pu; pd_p=g_pd; su_p=g_su; sd_p=g_sd;
      sv_p=g_sv[(which+1)&1]; res_p=sv_p; out_p=g_sv[which&1]; break;
    case 4: pu_p=g_pu; pd_p=g_pd; su_p=g_su; sd_p=g_sd; sv_p=g_sv[1]; out_p=g_hu; break;
    case 5: pu_p=g_pu; pd_p=g_pd; su_p=g_su; sd_p=g_sd; sv_p=g_sv[1]; out_p=g_hd; row0=256; break;
    case 6: sv_p=g_hu; out_p=g_orbu; rs_p=g_f;       dotanh=0; break;
    default: sv_p=g_hd; out_p=g_orbd; rs_p=g_f+256;  dotanh=0; break;
  }
  int t = threadIdx.x;
  int rg = blockIdx.x, cg = blockIdx.y;
  int col0 = cg * 32;
  for (int idx = t; idx < MAINK*32; idx += 256) {
    int c = idx >> 5, cl = idx & 31;
    wsl[idx] = W[(2*MEANK + c)*256 + col0 + cl];
  }
  for (int rr = 0; rr < 32; ++rr) {
    int row = row0 + rg*32 + rr;
    for (int c = t; c < MAINK; c += 256) {
      float v;
      if (c < PUK) v = pu_p[row*PUK + c];
      else if (c < 2*PUK) v = pd_p[row*PUK + (c - PUK)];
      else v = sv_p[row*SVK + (c - 2*PUK)];
      insl[rr*(MAINK+1) + c] = v;
    }
  }
  {
    int pcol = t & 31, ps = t >> 5;
    float bacc = 0.f;
    if (MEANK > 0) {
      for (int c = ps; c < MEANK; c += 8)
        bacc += su_p[c]*W[c*256 + col0 + pcol] + sd_p[c]*W[(MEANK + c)*256 + col0 + pcol];
    }
    bred[ps*32 + pcol] = bacc;
  }
  __syncthreads();
  if (t < 32) {
    float s = Wb[col0 + t];
    #pragma unroll
    for (int p8 = 0; p8 < 8; ++p8) s += bred[p8*32 + t];
    biasv[t] = s;
  }
  __syncthreads();
  int c4 = t & 7, rl = t >> 3;
  float a0 = biasv[4*c4], a1 = biasv[4*c4+1], a2 = biasv[4*c4+2], a3 = biasv[4*c4+3];
  const float* inrow = &insl[rl*(MAINK+1)];
  for (int c = 0; c < MAINK; ++c) {
    float iv = inrow[c];
    float4 wv = *(const float4*)&wsl[c*32 + 4*c4];
    a0 += iv*wv.x; a1 += iv*wv.y; a2 += iv*wv.z; a3 += iv*wv.w;
  }
  int rowA = rg*32 + rl;
  int col = col0 + 4*c4;
  if (dotanh) { a0=tanh_fast(a0); a1=tanh_fast(a1); a2=tanh_fast(a2); a3=tanh_fast(a3); }
  if (res_p) {
    float4 rv = *(const float4*)&res_p[rowA*256 + col];
    a0 += rv.x; a1 += rv.y; a2 += rv.z; a3 += rv.w;
  }
  if (rs_p) { float fsc = rs_p[rowA]; a0*=fsc; a1*=fsc; a2*=fsc; a3*=fsc; }
  float4 ov; ov.x=a0; ov.y=a1; ov.z=a2; ov.w=a3;
  *(float4*)&out_p[rowA*256 + col] = ov;
}

// ---------------- register-resident LU, 2-D tiles (v6) ----------------
// v4 (305us, 2860cy/col) + chain cuts: DPP max-reduce (VALU) replaces ds_swizzle
// shfl chain; exact pivot via 4 uniform readlanes (no colbuf[p] LDS read on chain);
// frexp-accumulate replaces per-iter logf; trailing-column 'alive' skip (halves
// average phase-U FMA issue). Multiplier-source colbuf reads hoisted above reduce.
#define REP8(M) M(0) M(1) M(2) M(3) M(4) M(5) M(6) M(7)
#define DPPMAX(v, CTRL) { unsigned _o = (unsigned)__builtin_amdgcn_update_dpp(0, (int)(v), CTRL, 0xf, 0xf, true); \
                          (v) = (v) > _o ? (v) : _o; }

__global__ __launch_bounds__(512, 2) void k_lu() {
  __shared__ __align__(16) float colbuf[256];
  __shared__ __align__(16) float prowbuf[16*68];     // group c at word 68c (padded)
  const float* A = (blockIdx.x == 0) ? g_orbu : g_orbd;
  int t = threadIdx.x;
  int tile_r = t >> 4;        // 0..31 -> rows 8*tile_r .. +7
  int tile_c = t & 15;        // 0..15 -> cols 16*tile_c .. +15
  int lane = t & 63;
  int br = tile_r * 8;
  int pb = tile_c * 68;
  const float4* Ap = (const float4*)(A + (tile_r*8)*256 + tile_c*16);
  // row stride = 64 float4
#define DECLROW(R) float4 M##R##_0 = Ap[R*64+0], M##R##_1 = Ap[R*64+1], \
                          M##R##_2 = Ap[R*64+2], M##R##_3 = Ap[R*64+3];
  REP8(DECLROW)
#undef DECLROW
  unsigned um = 0;            // used-mask for candidate rows 4*lane..4*lane+3
  if (tile_c == 0) {
#define INIT0(R) colbuf[br+R] = M##R##_0.x;
    REP8(INIT0)
#undef INIT0
  }
  __syncthreads();
  float prod = 1.f;
  int esum = 0;
  for (int k = 0; k < 256; ++k) {
    // ---- phase S: pivot search on colbuf (holds column k) ----
    float4 cv = *(const float4*)&colbuf[4*lane];    // candidate rows for this lane
    float4 ca = *(const float4*)&colbuf[br];        // multiplier sources (hoisted)
    float4 cb = *(const float4*)&colbuf[br+4];
    unsigned b0 = (um & 1u) ? 0u : ((__float_as_uint(fabsf(cv.x)) & 0xFFFFFF00u) | (unsigned)(4*lane+0));
    unsigned b1 = (um & 2u) ? 0u : ((__float_as_uint(fabsf(cv.y)) & 0xFFFFFF00u) | (unsigned)(4*lane+1));
    unsigned b2 = (um & 4u) ? 0u : ((__float_as_uint(fabsf(cv.z)) & 0xFFFFFF00u) | (unsigned)(4*lane+2));
    unsigned b3 = (um & 8u) ? 0u : ((__float_as_uint(fabsf(cv.w)) & 0xFFFFFF00u) | (unsigned)(4*lane+3));
    unsigned bb = max(max(b0,b1), max(b2,b3));
    // 64-lane max via DPP (row_shr 1/2/4/8 + row_bcast 15/31), result in lane 63
    DPPMAX(bb, 0x111) DPPMAX(bb, 0x112) DPPMAX(bb, 0x114) DPPMAX(bb, 0x118)
    DPPMAX(bb, 0x142) DPPMAX(bb, 0x143)
    bb = (unsigned)__builtin_amdgcn_readlane((int)bb, 63);
    int p = (int)(bb & 255u);
    int wl = p >> 2, cc = p & 3;
    // exact pivot via uniform readlanes of the winner lane's candidate float4
    unsigned px = (unsigned)__builtin_amdgcn_readlane((int)__float_as_uint(cv.x), wl);
    unsigned py = (unsigned)__builtin_amdgcn_readlane((int)__float_as_uint(cv.y), wl);
    unsigned pz = (unsigned)__builtin_amdgcn_readlane((int)__float_as_uint(cv.z), wl);
    unsigned pw = (unsigned)__builtin_amdgcn_readlane((int)__float_as_uint(cv.w), wl);
    float piv = __uint_as_float(cc==0 ? px : cc==1 ? py : cc==2 ? pz : pw);
    // frexp-accumulate log|piv| (no transcendental on the loop)
    int ee; float mant = frexpf(fabsf(piv), &ee);
    prod *= mant; esum += ee;
    int e2; prod = frexpf(prod, &e2); esum += e2;   // keep prod in [0.25,1)
    if (wl == lane) um |= 1u << cc;
    if (k == 255) break;
    float rp = 1.0f / piv;
    float m0 = ca.x*rp, m1 = ca.y*rp, m2 = ca.z*rp, m3 = ca.w*rp;
    float m4 = cb.x*rp, m5 = cb.y*rp, m6 = cb.z*rp, m7 = cb.w*rp;
    bool alive = (tile_c*16 + 15) > k;
    // pivot-row owners publish their 16-col slice (uniform switch on p&7)
    if (alive && tile_r == (p >> 3)) {
      switch (p & 7) {
#define PUBC(R) case R: *(float4*)&prowbuf[pb+0] = M##R##_0; *(float4*)&prowbuf[pb+4] = M##R##_1; \
                        *(float4*)&prowbuf[pb+8] = M##R##_2; *(float4*)&prowbuf[pb+12] = M##R##_3; break;
        REP8(PUBC)
#undef PUBC
      }
    }
    __syncthreads();
    // ---- phase U: rank-1 update (alive tiles only) + extract column k+1 ----
    if (alive) {
      float4 P0 = *(const float4*)&prowbuf[pb+0];
      float4 P1 = *(const float4*)&prowbuf[pb+4];
      float4 P2 = *(const float4*)&prowbuf[pb+8];
      float4 P3 = *(const float4*)&prowbuf[pb+12];
#define UPD(R) { float mr = m##R; \
  M##R##_0.x -= mr*P0.x; M##R##_0.y -= mr*P0.y; M##R##_0.z -= mr*P0.z; M##R##_0.w -= mr*P0.w; \
  M##R##_1.x -= mr*P1.x; M##R##_1.y -= mr*P1.y; M##R##_1.z -= mr*P1.z; M##R##_1.w -= mr*P1.w; \
  M##R##_2.x -= mr*P2.x; M##R##_2.y -= mr*P2.y; M##R##_2.z -= mr*P2.z; M##R##_2.w -= mr*P2.w; \
  M##R##_3.x -= mr*P3.x; M##R##_3.y -= mr*P3.y; M##R##_3.z -= mr*P3.z; M##R##_3.w -= mr*P3.w; }
      REP8(UPD)
#undef UPD
      int kn = k + 1;
      if (tile_c == (kn >> 4)) {
        switch (kn & 15) {
#define EXTC(I, G, C) case I: { colbuf[br+0]=M0_##G.C; colbuf[br+1]=M1_##G.C; \
  colbuf[br+2]=M2_##G.C; colbuf[br+3]=M3_##G.C; colbuf[br+4]=M4_##G.C; \
  colbuf[br+5]=M5_##G.C; colbuf[br+6]=M6_##G.C; colbuf[br+7]=M7_##G.C; } break;
          EXTC(0,0,x) EXTC(1,0,y) EXTC(2,0,z) EXTC(3,0,w)
          EXTC(4,1,x) EXTC(5,1,y) EXTC(6,1,z) EXTC(7,1,w)
          EXTC(8,2,x) EXTC(9,2,y) EXTC(10,2,z) EXTC(11,2,w)
          EXTC(12,3,x) EXTC(13,3,y) EXTC(14,3,z) EXTC(15,3,w)
#undef EXTC
        }
      }
    }
    __syncthreads();
  }
  if (t == 0) g_logs[blockIdx.x] = logf(prod) + (float)esum * 0.69314718055994531f;
}

__global__ void k_final(float* out) { out[0] = g_logs[0] + g_logs[1]; }

// ---------------- launch ----------------
extern "C" void kernel_launch(void* const* d_in, const int* in_sizes, int n_in,
                              void* d_out, int out_size, void* d_ws, size_t ws_size,
                              hipStream_t stream) {
  const float* r     = (const float*)d_in[0];
  const float* a     = (const float*)d_in[1];
  const float* V0_W  = (const float*)d_in[2];
  const float* V0_b  = (const float*)d_in[3];
  const float* Vr_W  = (const float*)d_in[4];
  const float* Vr_b  = (const float*)d_in[5];
  const float* W0_W  = (const float*)d_in[6];
  const float* W0_b  = (const float*)d_in[7];
  const float* Wr_W  = (const float*)d_in[8];
  const float* Wr_b  = (const float*)d_in[9];
  const float* Vhu_W = (const float*)d_in[10];
  const float* Vhu_b = (const float*)d_in[11];
  const float* Vhd_W = (const float*)d_in[12];
  const float* Vhd_b = (const float*)d_in[13];
  const float* wu_W  = (const float*)d_in[14];
  const float* wu_b  = (const float*)d_in[15];
  const float* wd_W  = (const float*)d_in[16];
  const float* wd_b  = (const float*)d_in[17];
  float* out = (float*)d_out;

  k_geom<<<1, 512, 0, stream>>>(r, a);
  k_pmean0<<<512, 256, 0, stream>>>(r);

  // layer 0
  k_smm<4,64,64><<<dim3(16,8), 256, 0, stream>>>(0, V0_W, V0_b);
  k_pup<0><<<1024, 256, 0, stream>>>(W0_W, W0_b, r, 0, 0);
  k_reduce<<<258, 256, 0, stream>>>(0);
  // layer 1
  k_smm<64,256,256><<<dim3(16,8), 256, 0, stream>>>(1, Vr_W + 0*896*256, Vr_b + 0);
  k_pup<1><<<1024, 256, 0, stream>>>(Wr_W + 0*4096, Wr_b + 0, r, 0, 1);
  k_reduce<<<258, 256, 0, stream>>>(1);
  // layer 2
  k_smm<64,256,256><<<dim3(16,8), 256, 0, stream>>>(2, Vr_W + 1*896*256, Vr_b + 256);
  k_pup<1><<<1024, 256, 0, stream>>>(Wr_W + 1*4096, Wr_b + 64, r, 1, 0);
  k_reduce<<<258, 256, 0, stream>>>(0);
  // layer 3 (p4 not stored; only its means)
  k_smm<64,256,256><<<dim3(16,8), 256, 0, stream>>>(3, Vr_W + 2*896*256, Vr_b + 512);
  k_pup<2><<<1024, 256, 0, stream>>>(Wr_W + 2*4096, Wr_b + 128, r, 0, 0);
  k_reduce<<<258, 256, 0, stream>>>(1);
  // heads
  k_smm<64,256,256><<<dim3(8,8), 256, 0, stream>>>(4, Vhu_W, Vhu_b);
  k_smm<64,256,256><<<dim3(8,8), 256, 0, stream>>>(5, Vhd_W, Vhd_b);
  // orbitals
  k_smm<0,256,0><<<dim3(8,8), 256, 0, stream>>>(6, wu_W, wu_b);
  k_smm<0,256,0><<<dim3(8,8), 256, 0, stream>>>(7, wd_W, wd_b);
  // log|det| x2 and combine
  k_lu<<<2, 512, 0, stream>>>();
  k_final<<<1, 1, 0, stream>>>(out);
}

// Round 9
// 754.676 us; speedup vs baseline: 2.4611x; 1.0357x over previous
//
#include <hip/hip_runtime.h>
#include <hip/hip_bf16.h>

#define NE 512

// ---------------- static device buffers (avoid d_ws dependence) ----------------
__device__ __align__(16) float g_p[2][NE*NE*64];     // ping-pong pair features (67MB each)
__device__ __align__(16) float g_sv0[NE*64];
__device__ __align__(16) float g_sv[2][NE*256];
__device__ __align__(16) float g_pu4[NE*4];
__device__ __align__(16) float g_pd4[NE*4];
__device__ __align__(16) float g_pu[NE*64];
__device__ __align__(16) float g_pd[NE*64];
__device__ __align__(16) float g_su0[64];
__device__ __align__(16) float g_sd0[64];
__device__ __align__(16) float g_su[256];
__device__ __align__(16) float g_sd[256];
__device__ __align__(16) float g_part[8*NE*64];      // per-(j,chunk) partial means of p
__device__ __align__(16) float g_f[NE];              // sum_a exp(-|r_i - a|)
__device__ __align__(16) float g_hu[256*256];
__device__ __align__(16) float g_hd[256*256];
__device__ __align__(16) float g_orbu[256*256];
__device__ __align__(16) float g_orbd[256*256];
__device__ float g_logs[2];

__device__ __forceinline__ float tanh_fast(float x) {
  float e = __expf(2.f * x);
  return 1.f - 2.f / (e + 1.f);
}

// ---------------- K0 fused: pmean0 (all blocks) + geometry/s_v0/f (block 0) ----------
__global__ __launch_bounds__(256) void k_pgeom(const float* __restrict__ r,
                                               const float* __restrict__ a) {
  int j = blockIdx.x, t = threadIdx.x;
  if (j == 0) {
    // geometry features for 512 electrons (2 per thread)
    for (int h = 0; h < 2; ++h) {
      int e = h*256 + t;
      float rx = r[3*e], ry = r[3*e+1], rz = r[3*e+2];
      float facc = 0.f;
      #pragma unroll
      for (int at = 0; at < 16; ++at) {
        float dx = rx - a[3*at], dy = ry - a[3*at+1], dz = rz - a[3*at+2];
        float len = sqrtf(dx*dx + dy*dy + dz*dz);
        g_sv0[e*64 + 4*at + 0] = dx;
        g_sv0[e*64 + 4*at + 1] = dy;
        g_sv0[e*64 + 4*at + 2] = dz;
        g_sv0[e*64 + 4*at + 3] = len;
        facc += expf(-len);
      }
      g_f[e] = facc;
    }
    __syncthreads();
    if (t < 128) {
      int h = t >> 6, c = t & 63;
      float s = 0.f;
      for (int i = 0; i < 256; ++i) s += g_sv0[(h*256 + i)*64 + c];
      (h ? g_sd0 : g_su0)[c] = s * (1.f/256.f);
    }
    __syncthreads();
  }
  // p0 means for this j
  float rjx = r[3*j], rjy = r[3*j+1], rjz = r[3*j+2];
  __shared__ float red[4][4];
  for (int h = 0; h < 2; ++h) {
    int i = h*256 + t;
    float dx = rjx - r[3*i], dy = rjy - r[3*i+1], dz = rjz - r[3*i+2];
    float ee = (i == j) ? 1.f : 0.f;
    float ex = dx+ee, ey = dy+ee, ez = dz+ee;
    float len = sqrtf(ex*ex + ey*ey + ez*ez);
    float v0 = dx, v1 = dy, v2 = dz, v3 = len;
    #pragma unroll
    for (int m = 1; m < 64; m <<= 1) {
      v0 += __shfl_xor(v0, m); v1 += __shfl_xor(v1, m);
      v2 += __shfl_xor(v2, m); v3 += __shfl_xor(v3, m);
    }
    if ((t & 63) == 0) {
      int wv = t >> 6;
      red[wv][0]=v0; red[wv][1]=v1; red[wv][2]=v2; red[wv][3]=v3;
    }
    __syncthreads();
    if (t == 0) {
      float* dst = h ? g_pd4 : g_pu4;
      #pragma unroll
      for (int c = 0; c < 4; ++c)
        dst[j*4 + c] = (red[0][c]+red[1][c]+red[2][c]+red[3][c]) * (1.f/256.f);
    }
    __syncthreads();
  }
}

// ---------------- p-channel update. MODE 0: from geometry; 1: load+store; 2: load only ----
// Best measured variant (R4/R8): wave-uniform LDS broadcast of the row.
template<int MODE>
__global__ __launch_bounds__(256) void k_pup(const float* __restrict__ W,
                                             const float* __restrict__ Wb,
                                             const float* __restrict__ r,
                                             int src, int dst) {
  __shared__ __align__(16) float psh[4][64];
  int t = threadIdx.x, lane = t & 63, wv = t >> 6;
  int gw = blockIdx.x*4 + wv;          // 0..4095
  int j = gw >> 3, chunk = gw & 7;
  int i0 = chunk * 64;
  float macc = 0.f;
  if (MODE == 0) {
    float w0 = W[lane], w1 = W[64+lane], w2 = W[128+lane], w3 = W[192+lane];
    float bb = Wb[lane];
    float rjx = r[3*j], rjy = r[3*j+1], rjz = r[3*j+2];
    float* pout = g_p[0];
    for (int ii = 0; ii < 64; ++ii) {
      int i = i0 + ii;
      float dx = rjx - r[3*i], dy = rjy - r[3*i+1], dz = rjz - r[3*i+2];
      float ee = (i == j) ? 1.f : 0.f;
      float ex = dx+ee, ey = dy+ee, ez = dz+ee;
      float len = sqrtf(ex*ex + ey*ey + ez*ez);
      float y = tanh_fast(bb + dx*w0 + dy*w1 + dz*w2 + len*w3);
      pout[(i*NE + j)*64 + lane] = y;
      macc += y;
    }
  } else {
    const float* pin = g_p[src];
    float* pout = g_p[dst];
    float wcol[64];
    #pragma unroll
    for (int k = 0; k < 64; ++k) wcol[k] = W[k*64 + lane];
    float bb = Wb[lane];
    for (int ii = 0; ii < 64; ++ii) {
      int i = i0 + ii;
      int base = (i*NE + j)*64;
      float x = pin[base + lane];
      psh[wv][lane] = x;
      float acc = bb;
      #pragma unroll
      for (int g = 0; g < 16; ++g) {
        float4 pv = *(const float4*)&psh[wv][4*g];   // wave-uniform broadcast reads
        acc += pv.x*wcol[4*g] + pv.y*wcol[4*g+1] + pv.z*wcol[4*g+2] + pv.w*wcol[4*g+3];
      }
      float y = tanh_fast(acc) + x;                  // residual (layers >= 1)
      if (MODE == 1) pout[base + lane] = y;
      macc += y;
    }
  }
  g_part[chunk*(NE*64) + j*64 + lane] = macc;
}

// ---------------- finalize p-means + s-means ----------------
__global__ __launch_bounds__(256) void k_reduce(int svsel) {
  int bid = blockIdx.x, t = threadIdx.x;
  if (bid < 256) {
    int idx = bid*256 + t;
    int half = idx >> 15, rem = idx & 32767;
    int j = rem >> 6, l = rem & 63;
    const float* pp = g_part + half*(4*NE*64);
    float s = pp[0*(NE*64)+j*64+l] + pp[1*(NE*64)+j*64+l]
            + pp[2*(NE*64)+j*64+l] + pp[3*(NE*64)+j*64+l];
    (half ? g_pd : g_pu)[j*64 + l] = s * (1.f/256.f);
  } else {
    int h = bid - 256;
    const float* sv = g_sv[svsel];
    float s = 0.f;
    for (int i = 0; i < 256; ++i) s += sv[(h*256 + i)*256 + t];
    (h ? g_sd : g_su)[t] = s * (1.f/256.f);
  }
}

// ---------------- generic s-channel matmul ----------------
// which: 0=layer0, 1..3=layer l, 4=FUSED heads (u:rg<8, d:rg>=8), 6=FUSED orbitals
template<int PUK, int SVK, int MEANK>
__global__ __launch_bounds__(256) void k_smm(int which, const float* __restrict__ W,
                                             const float* __restrict__ Wb,
                                             const float* __restrict__ W2,
                                             const float* __restrict__ Wb2) {
  constexpr int MAINK = 2*PUK + SVK;
  __shared__ __align__(16) float wsl[MAINK*32];
  __shared__ float insl[32*(MAINK+1)];
  __shared__ float biasv[32];
  __shared__ float bred[256];
  const float *pu_p=nullptr, *pd_p=nullptr, *sv_p=nullptr, *su_p=nullptr, *sd_p=nullptr;
  const float *res_p=nullptr, *rs_p=nullptr;
  float* out_p = nullptr;
  int t = threadIdx.x;
  int rg = blockIdx.x, cg = blockIdx.y;
  int grp = 0, rgl = rg;
  if (which >= 4) { grp = rg >> 3; rgl = rg & 7; }
  const float* Wsel = (which >= 4 && grp) ? W2 : W;
  const float* Wbsel = (which >= 4 && grp) ? Wb2 : Wb;
  int in_base = 0, dotanh = 1;
  switch (which) {
    case 0: pu_p=g_pu4; pd_p=g_pd4; su_p=g_su0; sd_p=g_sd0; sv_p=g_sv0;
            out_p=g_sv[0]; in_base=rg*32; break;
    case 1: case 2: case 3:
      pu_p=g_pu; pd_p=g_pd; su_p=g_su; sd_p=g_sd;
      sv_p=g_sv[(which+1)&1]; res_p=sv_p; out_p=g_sv[which&1]; in_base=rg*32; break;
    case 4: pu_p=g_pu; pd_p=g_pd; su_p=g_su; sd_p=g_sd; sv_p=g_sv[1];
            out_p = grp ? g_hd : g_hu; in_base = grp*256 + rgl*32; break;
    default: sv_p = grp ? g_hd : g_hu; out_p = grp ? g_orbd : g_orbu;
             rs_p = g_f + grp*256; in_base = rgl*32; dotanh = 0; break;
  }
  int out_base = (which >= 4) ? rgl*32 : rg*32;
  int col0 = cg * 32;
  for (int idx = t; idx < MAINK*32; idx += 256) {
    int c = idx >> 5, cl = idx & 31;
    wsl[idx] = Wsel[(2*MEANK + c)*256 + col0 + cl];
  }
  for (int rr = 0; rr < 32; ++rr) {
    int row = in_base + rr;
    for (int c = t; c < MAINK; c += 256) {
      float v;
      if (c < PUK) v = pu_p[row*PUK + c];
      else if (c < 2*PUK) v = pd_p[row*PUK + (c - PUK)];
      else v = sv_p[row*SVK + (c - 2*PUK)];
      insl[rr*(MAINK+1) + c] = v;
    }
  }
  {
    int pcol = t & 31, ps = t >> 5;
    float bacc = 0.f;
    if (MEANK > 0) {
      for (int c = ps; c < MEANK; c += 8)
        bacc += su_p[c]*Wsel[c*256 + col0 + pcol] + sd_p[c]*Wsel[(MEANK + c)*256 + col0 + pcol];
    }
    bred[ps*32 + pcol] = bacc;
  }
  __syncthreads();
  if (t < 32) {
    float s = Wbsel[col0 + t];
    #pragma unroll
    for (int p8 = 0; p8 < 8; ++p8) s += bred[p8*32 + t];
    biasv[t] = s;
  }
  __syncthreads();
  int c4 = t & 7, rl = t >> 3;
  float a0 = biasv[4*c4], a1 = biasv[4*c4+1], a2 = biasv[4*c4+2], a3 = biasv[4*c4+3];
  const float* inrow = &insl[rl*(MAINK+1)];
  #pragma unroll 4
  for (int c = 0; c < MAINK; ++c) {
    float iv = inrow[c];
    float4 wv = *(const float4*)&wsl[c*32 + 4*c4];
    a0 += iv*wv.x; a1 += iv*wv.y; a2 += iv*wv.z; a3 += iv*wv.w;
  }
  int rowA = out_base + rl;
  int col = col0 + 4*c4;
  if (dotanh) { a0=tanh_fast(a0); a1=tanh_fast(a1); a2=tanh_fast(a2); a3=tanh_fast(a3); }
  if (res_p) {
    float4 rv = *(const float4*)&res_p[rowA*256 + col];
    a0 += rv.x; a1 += rv.y; a2 += rv.z; a3 += rv.w;
  }
  if (rs_p) { float fsc = rs_p[rowA]; a0*=fsc; a1*=fsc; a2*=fsc; a3*=fsc; }
  float4 ov; ov.x=a0; ov.y=a1; ov.z=a2; ov.w=a3;
  *(float4*)&out_p[rowA*256 + col] = ov;
}

// ---------------- register-resident LU, v7: 1024 threads, 8x8 tiles ----------------
// R8: v6 at 283us, per-active-CU VALUBusy ~51%, phase-U issue (128 FMA/thread @
// 2 waves/SIMD) is the largest VALU block. v7: 1024 threads (4 waves/SIMD), each
// owns 8 rows x 8 cols -> 64 FMA/thread/iter; same 2 barriers; v6 chain features
// kept (DPP max-reduce, readlane pivot, frexp-accumulate, alive skip).
#define REP8(M) M(0) M(1) M(2) M(3) M(4) M(5) M(6) M(7)
#define DPPMAX(v, CTRL) { unsigned _o = (unsigned)__builtin_amdgcn_update_dpp(0, (int)(v), CTRL, 0xf, 0xf, true); \
                          (v) = (v) > _o ? (v) : _o; }

__global__ __launch_bounds__(1024, 4) void k_lu() {
  __shared__ __align__(16) float colbuf[256];
  __shared__ __align__(16) float prowbuf[32*12];     // group c at word 12c (8 used, padded)
  const float* A = (blockIdx.x == 0) ? g_orbu : g_orbd;
  int t = threadIdx.x;
  int tile_r = t >> 5;        // 0..31 -> rows 8*tile_r .. +7
  int tile_c = t & 31;        // 0..31 -> cols 8*tile_c .. +7
  int lane = t & 63;
  int br = tile_r * 8;
  int pb = tile_c * 12;
  const float4* Ap = (const float4*)(A + br*256 + tile_c*8);
  // row stride = 64 float4
#define DECLROW(R) float4 M##R##_0 = Ap[R*64+0], M##R##_1 = Ap[R*64+1];
  REP8(DECLROW)
#undef DECLROW
  unsigned um = 0;            // used-mask for candidate rows 4*lane..4*lane+3
  if (tile_c == 0) {
#define INIT0(R) colbuf[br+R] = M##R##_0.x;
    REP8(INIT0)
#undef INIT0
  }
  __syncthreads();
  float prod = 1.f;
  int esum = 0;
  for (int k = 0; k < 256; ++k) {
    // ---- phase S: pivot search on colbuf (holds column k) ----
    float4 cv = *(const float4*)&colbuf[4*lane];    // candidate rows for this lane
    float4 ca = *(const float4*)&colbuf[br];        // multiplier sources (hoisted)
    float4 cb = *(const float4*)&colbuf[br+4];
    unsigned b0 = (um & 1u) ? 0u : ((__float_as_uint(fabsf(cv.x)) & 0xFFFFFF00u) | (unsigned)(4*lane+0));
    unsigned b1 = (um & 2u) ? 0u : ((__float_as_uint(fabsf(cv.y)) & 0xFFFFFF00u) | (unsigned)(4*lane+1));
    unsigned b2 = (um & 4u) ? 0u : ((__float_as_uint(fabsf(cv.z)) & 0xFFFFFF00u) | (unsigned)(4*lane+2));
    unsigned b3 = (um & 8u) ? 0u : ((__float_as_uint(fabsf(cv.w)) & 0xFFFFFF00u) | (unsigned)(4*lane+3));
    unsigned bb = max(max(b0,b1), max(b2,b3));
    DPPMAX(bb, 0x111) DPPMAX(bb, 0x112) DPPMAX(bb, 0x114) DPPMAX(bb, 0x118)
    DPPMAX(bb, 0x142) DPPMAX(bb, 0x143)
    bb = (unsigned)__builtin_amdgcn_readlane((int)bb, 63);
    int p = (int)(bb & 255u);
    int wl = p >> 2, cc = p & 3;
    unsigned px = (unsigned)__builtin_amdgcn_readlane((int)__float_as_uint(cv.x), wl);
    unsigned py = (unsigned)__builtin_amdgcn_readlane((int)__float_as_uint(cv.y), wl);
    unsigned pz = (unsigned)__builtin_amdgcn_readlane((int)__float_as_uint(cv.z), wl);
    unsigned pw = (unsigned)__builtin_amdgcn_readlane((int)__float_as_uint(cv.w), wl);
    float piv = __uint_as_float(cc==0 ? px : cc==1 ? py : cc==2 ? pz : pw);
    int ee; float mant = frexpf(fabsf(piv), &ee);
    prod *= mant; esum += ee;
    int e2; prod = frexpf(prod, &e2); esum += e2;   // keep prod in [0.25,1)
    if (wl == lane) um |= 1u << cc;
    if (k == 255) break;
    float rp = 1.0f / piv;
    float m0 = ca.x*rp, m1 = ca.y*rp, m2 = ca.z*rp, m3 = ca.w*rp;
    float m4 = cb.x*rp, m5 = cb.y*rp, m6 = cb.z*rp, m7 = cb.w*rp;
    bool alive = (tile_c*8 + 7) > k;
    // pivot-row owners publish their 8-col slice (uniform switch on p&7)
    if (alive && tile_r == (p >> 3)) {
      switch (p & 7) {
#define PUBC(R) case R: *(float4*)&prowbuf[pb+0] = M##R##_0; *(float4*)&prowbuf[pb+4] = M##R##_1; break;
        REP8(PUBC)
#undef PUBC
      }
    }
    __syncthreads();
    // ---- phase U: rank-1 update (alive tiles only) + extract column k+1 ----
    if (alive) {
      float4 P0 = *(const float4*)&prowbuf[pb+0];
      float4 P1 = *(const float4*)&prowbuf[pb+4];
#define UPD(R) { float mr = m##R; \
  M##R##_0.x -= mr*P0.x; M##R##_0.y -= mr*P0.y; M##R##_0.z -= mr*P0.z; M##R##_0.w -= mr*P0.w; \
  M##R##_1.x -= mr*P1.x; M##R##_1.y -= mr*P1.y; M##R##_1.z -= mr*P1.z; M##R##_1.w -= mr*P1.w; }
      REP8(UPD)
#undef UPD
      int kn = k + 1;
      if (tile_c == (kn >> 3)) {
        switch (kn & 7) {
#define EXTC(I, G, C) case I: { colbuf[br+0]=M0_##G.C; colbuf[br+1]=M1_##G.C; \
  colbuf[br+2]=M2_##G.C; colbuf[br+3]=M3_##G.C; colbuf[br+4]=M4_##G.C; \
  colbuf[br+5]=M5_##G.C; colbuf[br+6]=M6_##G.C; colbuf[br+7]=M7_##G.C; } break;
          EXTC(0,0,x) EXTC(1,0,y) EXTC(2,0,z) EXTC(3,0,w)
          EXTC(4,1,x) EXTC(5,1,y) EXTC(6,1,z) EXTC(7,1,w)
#undef EXTC
        }
      }
    }
    __syncthreads();
  }
  if (t == 0) g_logs[blockIdx.x] = logf(prod) + (float)esum * 0.69314718055994531f;
}

__global__ void k_final(float* out) { out[0] = g_logs[0] + g_logs[1]; }

// ---------------- launch ----------------
extern "C" void kernel_launch(void* const* d_in, const int* in_sizes, int n_in,
                              void* d_out, int out_size, void* d_ws, size_t ws_size,
                              hipStream_t stream) {
  const float* r     = (const float*)d_in[0];
  const float* a     = (const float*)d_in[1];
  const float* V0_W  = (const float*)d_in[2];
  const float* V0_b  = (const float*)d_in[3];
  const float* Vr_W  = (const float*)d_in[4];
  const float* Vr_b  = (const float*)d_in[5];
  const float* W0_W  = (const float*)d_in[6];
  const float* W0_b  = (const float*)d_in[7];
  const float* Wr_W  = (const float*)d_in[8];
  const float* Wr_b  = (const float*)d_in[9];
  const float* Vhu_W = (const float*)d_in[10];
  const float* Vhu_b = (const float*)d_in[11];
  const float* Vhd_W = (const float*)d_in[12];
  const float* Vhd_b = (const float*)d_in[13];
  const float* wu_W  = (const float*)d_in[14];
  const float* wu_b  = (const float*)d_in[15];
  const float* wd_W  = (const float*)d_in[16];
  const float* wd_b  = (const float*)d_in[17];
  float* out = (float*)d_out;

  k_pgeom<<<512, 256, 0, stream>>>(r, a);

  // layer 0
  k_smm<4,64,64><<<dim3(16,8), 256, 0, stream>>>(0, V0_W, V0_b, nullptr, nullptr);
  k_pup<0><<<1024, 256, 0, stream>>>(W0_W, W0_b, r, 0, 0);
  k_reduce<<<258, 256, 0, stream>>>(0);
  // layer 1
  k_smm<64,256,256><<<dim3(16,8), 256, 0, stream>>>(1, Vr_W + 0*896*256, Vr_b + 0, nullptr, nullptr);
  k_pup<1><<<1024, 256, 0, stream>>>(Wr_W + 0*4096, Wr_b + 0, r, 0, 1);
  k_reduce<<<258, 256, 0, stream>>>(1);
  // layer 2
  k_smm<64,256,256><<<dim3(16,8), 256, 0, stream>>>(2, Vr_W + 1*896*256, Vr_b + 256, nullptr, nullptr);
  k_pup<1><<<1024, 256, 0, stream>>>(Wr_W + 1*4096, Wr_b + 64, r, 1, 0);
  k_reduce<<<258, 256, 0, stream>>>(0);
  // layer 3 (p4 not stored; only its means)
  k_smm<64,256,256><<<dim3(16,8), 256, 0, stream>>>(3, Vr_W + 2*896*256, Vr_b + 512, nullptr, nullptr);
  k_pup<2><<<1024, 256, 0, stream>>>(Wr_W + 2*4096, Wr_b + 128, r, 0, 0);
  k_reduce<<<258, 256, 0, stream>>>(1);
  // fused heads (u + d in one dispatch)
  k_smm<64,256,256><<<dim3(16,8), 256, 0, stream>>>(4, Vhu_W, Vhu_b, Vhd_W, Vhd_b);
  // fused orbitals (u + d in one dispatch)
  k_smm<0,256,0><<<dim3(16,8), 256, 0, stream>>>(6, wu_W, wu_b, wd_W, wd_b);
  // log|det| x2 and combine
  k_lu<<<2, 1024, 0, stream>>>();
  k_final<<<1, 1, 0, stream>>>(out);
}

// Round 10
// 636.582 us; speedup vs baseline: 2.9176x; 1.1855x over previous
//
#include <hip/hip_runtime.h>
#include <hip/hip_bf16.h>

#define NE 512

// ---------------- static device buffers ----------------
__device__ __align__(16) float g_p[2][NE*NE*64];     // ping-pong pair features
__device__ __align__(16) float g_sv0[NE*64];
__device__ __align__(16) float g_sv[2][NE*256];
__device__ __align__(16) float g_pu4[NE*4];
__device__ __align__(16) float g_pd4[NE*4];
__device__ __align__(16) float g_pu[NE*64];
__device__ __align__(16) float g_pd[NE*64];
__device__ __align__(16) float g_su0[64];
__device__ __align__(16) float g_sd0[64];
__device__ __align__(16) float g_su[256];
__device__ __align__(16) float g_sd[256];
__device__ __align__(16) float g_part[8*NE*64];
__device__ __align__(16) float g_f[NE];
__device__ __align__(16) float g_hu[256*256];
__device__ __align__(16) float g_hd[256*256];
__device__ __align__(16) float g_orbu[256*256];
__device__ __align__(16) float g_orbd[256*256];
__device__ float g_logs[2];

__device__ __forceinline__ float tanh_fast(float x) {
  float e = __expf(2.f * x);
  return 1.f - 2.f / (e + 1.f);
}

// ---------------- K0 fused: pmean0 (all blocks) + geometry/s_v0/f (block 0) ----------
__global__ __launch_bounds__(256) void k_pgeom(const float* __restrict__ r,
                                               const float* __restrict__ a) {
  int j = blockIdx.x, t = threadIdx.x;
  if (j == 0) {
    for (int h = 0; h < 2; ++h) {
      int e = h*256 + t;
      float rx = r[3*e], ry = r[3*e+1], rz = r[3*e+2];
      float facc = 0.f;
      #pragma unroll
      for (int at = 0; at < 16; ++at) {
        float dx = rx - a[3*at], dy = ry - a[3*at+1], dz = rz - a[3*at+2];
        float len = sqrtf(dx*dx + dy*dy + dz*dz);
        g_sv0[e*64 + 4*at + 0] = dx;
        g_sv0[e*64 + 4*at + 1] = dy;
        g_sv0[e*64 + 4*at + 2] = dz;
        g_sv0[e*64 + 4*at + 3] = len;
        facc += expf(-len);
      }
      g_f[e] = facc;
    }
    __syncthreads();
    if (t < 128) {
      int h = t >> 6, c = t & 63;
      float s = 0.f;
      for (int i = 0; i < 256; ++i) s += g_sv0[(h*256 + i)*64 + c];
      (h ? g_sd0 : g_su0)[c] = s * (1.f/256.f);
    }
    __syncthreads();
  }
  float rjx = r[3*j], rjy = r[3*j+1], rjz = r[3*j+2];
  __shared__ float red[4][4];
  for (int h = 0; h < 2; ++h) {
    int i = h*256 + t;
    float dx = rjx - r[3*i], dy = rjy - r[3*i+1], dz = rjz - r[3*i+2];
    float ee = (i == j) ? 1.f : 0.f;
    float ex = dx+ee, ey = dy+ee, ez = dz+ee;
    float len = sqrtf(ex*ex + ey*ey + ez*ez);
    float v0 = dx, v1 = dy, v2 = dz, v3 = len;
    #pragma unroll
    for (int m = 1; m < 64; m <<= 1) {
      v0 += __shfl_xor(v0, m); v1 += __shfl_xor(v1, m);
      v2 += __shfl_xor(v2, m); v3 += __shfl_xor(v3, m);
    }
    if ((t & 63) == 0) {
      int wv = t >> 6;
      red[wv][0]=v0; red[wv][1]=v1; red[wv][2]=v2; red[wv][3]=v3;
    }
    __syncthreads();
    if (t == 0) {
      float* dst = h ? g_pd4 : g_pu4;
      #pragma unroll
      for (int c = 0; c < 4; ++c)
        dst[j*4 + c] = (red[0][c]+red[1][c]+red[2][c]+red[3][c]) * (1.f/256.f);
    }
    __syncthreads();
  }
}

// ---------------- fused per-layer kernel: blocks 0..127 = smm, 128..1151 = pup -------
// smm uses K-chunked staging (64-wide) so LDS stays ~18KB and pup keeps occupancy.
template<int WHICH, int MODE, int PUK, int SVK, int MEANK>
__global__ __launch_bounds__(256) void k_layer(const float* __restrict__ VW,
                                               const float* __restrict__ Vb,
                                               const float* __restrict__ PW,
                                               const float* __restrict__ Pb,
                                               const float* __restrict__ r,
                                               int src, int dst) {
  constexpr int MAINK = 2*PUK + SVK;
  __shared__ __align__(16) float wsl[64*32];
  __shared__ __align__(16) float insl[32*68];
  __shared__ float biasv[32];
  __shared__ float bred[256];
  __shared__ __align__(16) float psh[4][64];
  int bid = blockIdx.x, t = threadIdx.x;
  if (bid < 128) {
    // ---- smm branch ----
    int rg = bid >> 3, cg = bid & 7, col0 = cg*32;
    const float *pu_p, *pd_p, *sv_p, *su_p, *sd_p, *res_p;
    float* out_p;
    if constexpr (WHICH == 0) {
      pu_p=g_pu4; pd_p=g_pd4; su_p=g_su0; sd_p=g_sd0; sv_p=g_sv0; res_p=nullptr; out_p=g_sv[0];
    } else {
      pu_p=g_pu; pd_p=g_pd; su_p=g_su; sd_p=g_sd;
      sv_p=g_sv[(WHICH+1)&1]; res_p=sv_p; out_p=g_sv[WHICH&1];
    }
    {
      int pcol = t & 31, ps = t >> 5;
      float bacc = 0.f;
      for (int c = ps; c < MEANK; c += 8)
        bacc += su_p[c]*VW[c*256 + col0 + pcol] + sd_p[c]*VW[(MEANK + c)*256 + col0 + pcol];
      bred[ps*32 + pcol] = bacc;
    }
    __syncthreads();
    if (t < 32) {
      float s = Vb[col0 + t];
      #pragma unroll
      for (int p8 = 0; p8 < 8; ++p8) s += bred[p8*32 + t];
      biasv[t] = s;
    }
    __syncthreads();
    int c4 = t & 7, rl = t >> 3;
    float a0 = biasv[4*c4], a1 = biasv[4*c4+1], a2 = biasv[4*c4+2], a3 = biasv[4*c4+3];
    int row_in = rg*32;
    #pragma unroll
    for (int c0 = 0; c0 < MAINK; c0 += 64) {
      const int CL = (MAINK - c0) < 64 ? (MAINK - c0) : 64;
      for (int idx = t; idx < CL*32; idx += 256) {
        int c = idx >> 5, cl = idx & 31;
        wsl[idx] = VW[(2*MEANK + c0 + c)*256 + col0 + cl];
      }
      {
        int rr = t >> 3;
        for (int c2 = (t & 7); c2 < CL; c2 += 8) {
          int c = c0 + c2, row = row_in + rr;
          float v;
          if (c < PUK) v = pu_p[row*PUK + c];
          else if (c < 2*PUK) v = pd_p[row*PUK + (c - PUK)];
          else v = sv_p[row*SVK + (c - 2*PUK)];
          insl[rr*68 + c2] = v;
        }
      }
      __syncthreads();
      const float* inrow = &insl[rl*68];
      #pragma unroll 4
      for (int c2 = 0; c2 < CL; ++c2) {
        float iv = inrow[c2];
        float4 wv = *(const float4*)&wsl[c2*32 + 4*c4];
        a0 += iv*wv.x; a1 += iv*wv.y; a2 += iv*wv.z; a3 += iv*wv.w;
      }
      __syncthreads();
    }
    int rowA = rg*32 + rl;
    int col = col0 + 4*c4;
    a0 = tanh_fast(a0); a1 = tanh_fast(a1); a2 = tanh_fast(a2); a3 = tanh_fast(a3);
    if (res_p) {
      float4 rv = *(const float4*)&res_p[rowA*256 + col];
      a0 += rv.x; a1 += rv.y; a2 += rv.z; a3 += rv.w;
    }
    float4 ov; ov.x=a0; ov.y=a1; ov.z=a2; ov.w=a3;
    *(float4*)&out_p[rowA*256 + col] = ov;
  } else {
    // ---- pup branch (best measured: wave-uniform LDS broadcast) ----
    int lane = t & 63, wv = t >> 6;
    int gw = (bid - 128)*4 + wv;          // 0..4095
    int j = gw >> 3, chunk = gw & 7;
    int i0 = chunk * 64;
    float macc = 0.f;
    if (MODE == 0) {
      float w0 = PW[lane], w1 = PW[64+lane], w2 = PW[128+lane], w3 = PW[192+lane];
      float bb = Pb[lane];
      float rjx = r[3*j], rjy = r[3*j+1], rjz = r[3*j+2];
      float* pout = g_p[0];
      for (int ii = 0; ii < 64; ++ii) {
        int i = i0 + ii;
        float dx = rjx - r[3*i], dy = rjy - r[3*i+1], dz = rjz - r[3*i+2];
        float ee = (i == j) ? 1.f : 0.f;
        float ex = dx+ee, ey = dy+ee, ez = dz+ee;
        float len = sqrtf(ex*ex + ey*ey + ez*ez);
        float y = tanh_fast(bb + dx*w0 + dy*w1 + dz*w2 + len*w3);
        pout[(i*NE + j)*64 + lane] = y;
        macc += y;
      }
    } else {
      const float* pin = g_p[src];
      float* pout = g_p[dst];
      float wcol[64];
      #pragma unroll
      for (int k = 0; k < 64; ++k) wcol[k] = PW[k*64 + lane];
      float bb = Pb[lane];
      for (int ii = 0; ii < 64; ++ii) {
        int i = i0 + ii;
        int base = (i*NE + j)*64;
        float x = pin[base + lane];
        psh[wv][lane] = x;
        float acc = bb;
        #pragma unroll
        for (int g = 0; g < 16; ++g) {
          float4 pv = *(const float4*)&psh[wv][4*g];
          acc += pv.x*wcol[4*g] + pv.y*wcol[4*g+1] + pv.z*wcol[4*g+2] + pv.w*wcol[4*g+3];
        }
        float y = tanh_fast(acc) + x;
        if (MODE == 1) pout[base + lane] = y;
        macc += y;
      }
    }
    g_part[chunk*(NE*64) + j*64 + lane] = macc;
  }
}

// ---------------- finalize p-means + s-means ----------------
__global__ __launch_bounds__(256) void k_reduce(int svsel) {
  int bid = blockIdx.x, t = threadIdx.x;
  if (bid < 256) {
    int idx = bid*256 + t;
    int half = idx >> 15, rem = idx & 32767;
    int j = rem >> 6, l = rem & 63;
    const float* pp = g_part + half*(4*NE*64);
    float s = pp[0*(NE*64)+j*64+l] + pp[1*(NE*64)+j*64+l]
            + pp[2*(NE*64)+j*64+l] + pp[3*(NE*64)+j*64+l];
    (half ? g_pd : g_pu)[j*64 + l] = s * (1.f/256.f);
  } else {
    int h = bid - 256;
    const float* sv = g_sv[svsel];
    float s = 0.f;
    for (int i = 0; i < 256; ++i) s += sv[(h*256 + i)*256 + t];
    (h ? g_sd : g_su)[t] = s * (1.f/256.f);
  }
}

// ---------------- heads / orbitals matmul (fused u+d via grp) ----------------
// which: 4=FUSED heads (grp = rg>>3), 6=FUSED orbitals
template<int PUK, int SVK, int MEANK>
__global__ __launch_bounds__(256) void k_smm(int which, const float* __restrict__ W,
                                             const float* __restrict__ Wb,
                                             const float* __restrict__ W2,
                                             const float* __restrict__ Wb2) {
  constexpr int MAINK = 2*PUK + SVK;
  __shared__ __align__(16) float wsl[MAINK*32];
  __shared__ float insl[32*(MAINK+1)];
  __shared__ float biasv[32];
  __shared__ float bred[256];
  const float *pu_p=nullptr, *pd_p=nullptr, *sv_p=nullptr, *su_p=nullptr, *sd_p=nullptr;
  const float *rs_p=nullptr;
  float* out_p = nullptr;
  int t = threadIdx.x;
  int rg = blockIdx.x, cg = blockIdx.y;
  int grp = rg >> 3, rgl = rg & 7;
  const float* Wsel = grp ? W2 : W;
  const float* Wbsel = grp ? Wb2 : Wb;
  int in_base = 0, dotanh = 1;
  if (which == 4) {
    pu_p=g_pu; pd_p=g_pd; su_p=g_su; sd_p=g_sd; sv_p=g_sv[1];
    out_p = grp ? g_hd : g_hu; in_base = grp*256 + rgl*32;
  } else {
    sv_p = grp ? g_hd : g_hu; out_p = grp ? g_orbd : g_orbu;
    rs_p = g_f + grp*256; in_base = rgl*32; dotanh = 0;
  }
  int out_base = rgl*32;
  int col0 = cg * 32;
  for (int idx = t; idx < MAINK*32; idx += 256) {
    int c = idx >> 5, cl = idx & 31;
    wsl[idx] = Wsel[(2*MEANK + c)*256 + col0 + cl];
  }
  for (int rr = 0; rr < 32; ++rr) {
    int row = in_base + rr;
    for (int c = t; c < MAINK; c += 256) {
      float v;
      if (c < PUK) v = pu_p[row*PUK + c];
      else if (c < 2*PUK) v = pd_p[row*PUK + (c - PUK)];
      else v = sv_p[row*SVK + (c - 2*PUK)];
      insl[rr*(MAINK+1) + c] = v;
    }
  }
  {
    int pcol = t & 31, ps = t >> 5;
    float bacc = 0.f;
    if (MEANK > 0) {
      for (int c = ps; c < MEANK; c += 8)
        bacc += su_p[c]*Wsel[c*256 + col0 + pcol] + sd_p[c]*Wsel[(MEANK + c)*256 + col0 + pcol];
    }
    bred[ps*32 + pcol] = bacc;
  }
  __syncthreads();
  if (t < 32) {
    float s = Wbsel[col0 + t];
    #pragma unroll
    for (int p8 = 0; p8 < 8; ++p8) s += bred[p8*32 + t];
    biasv[t] = s;
  }
  __syncthreads();
  int c4 = t & 7, rl = t >> 3;
  float a0 = biasv[4*c4], a1 = biasv[4*c4+1], a2 = biasv[4*c4+2], a3 = biasv[4*c4+3];
  const float* inrow = &insl[rl*(MAINK+1)];
  #pragma unroll 4
  for (int c = 0; c < MAINK; ++c) {
    float iv = inrow[c];
    float4 wv = *(const float4*)&wsl[c*32 + 4*c4];
    a0 += iv*wv.x; a1 += iv*wv.y; a2 += iv*wv.z; a3 += iv*wv.w;
  }
  int rowA = out_base + rl;
  int col = col0 + 4*c4;
  if (dotanh) { a0=tanh_fast(a0); a1=tanh_fast(a1); a2=tanh_fast(a2); a3=tanh_fast(a3); }
  if (rs_p) { float fsc = rs_p[rowA]; a0*=fsc; a1*=fsc; a2*=fsc; a3*=fsc; }
  float4 ov; ov.x=a0; ov.y=a1; ov.z=a2; ov.w=a3;
  *(float4*)&out_p[rowA*256 + col] = ov;
}

// ---------------- register-resident LU, v8: ONE barrier per column ----------------
// Column-major thread map: tile_c = t>>5 (16-col group = contiguous half-wave),
// tile_r = t&31 (8 rows). Double-buffered colbuf+prowbuf make all LDS lifetimes
// span <=2 regions (waves never >1 barrier apart -> race-free). The col-(k+1)
// pivot element is broadcast IN-REGISTER via __shfl from the owning lane of the
// half-wave, removing the publish->extract dependency that forced barrier #2.
// Region k: [update(k-1) || colbuf reads] -> DPP search -> mult -> publish prow_k
// -> extract col k+1 (shfl) -> ONE barrier. v6 chain features kept.
#define REP8(M) M(0) M(1) M(2) M(3) M(4) M(5) M(6) M(7)
#define DPPMAX(v, CTRL) { unsigned _o = (unsigned)__builtin_amdgcn_update_dpp(0, (int)(v), CTRL, 0xf, 0xf, true); \
                          (v) = (v) > _o ? (v) : _o; }

__global__ __launch_bounds__(512, 2) void k_lu() {
  __shared__ __align__(16) float colbuf[2][256];
  __shared__ __align__(16) float prowbuf[2][16*20];   // group c at word 20c (16 used)
  const float* A = (blockIdx.x == 0) ? g_orbu : g_orbd;
  int t = threadIdx.x;
  int tile_c = t >> 5;        // 0..15 -> cols 16*tile_c .. +15
  int tile_r = t & 31;        // 0..31 -> rows 8*tile_r .. +7
  int lane = t & 63;
  int br = tile_r * 8;
  int pb = tile_c * 20;
  const float4* Ap = (const float4*)(A + br*256 + tile_c*16);
#define DECLROW(R) float4 M##R##_0 = Ap[R*64+0], M##R##_1 = Ap[R*64+1], \
                          M##R##_2 = Ap[R*64+2], M##R##_3 = Ap[R*64+3];
  REP8(DECLROW)
#undef DECLROW
  unsigned um = 0;            // used-mask for candidate rows 4*lane..4*lane+3
  if (tile_c == 0) {
#define INIT0(R) colbuf[0][br+R] = M##R##_0.x;
    REP8(INIT0)
#undef INIT0
  }
  __syncthreads();
  float prod = 1.f;
  int esum = 0;
  float m0=0,m1=0,m2=0,m3=0,m4=0,m5=0,m6=0,m7=0;   // pending-update multipliers
  for (int k = 0; k < 256; ++k) {
    const float* cbin = colbuf[k & 1];
    float4 cv = *(const float4*)&cbin[4*lane];      // search candidates
    float4 ca = *(const float4*)&cbin[br];          // own rows (mult source)
    float4 cb2 = *(const float4*)&cbin[br+4];
    // ---- pending rank-1 update (k-1) ----
    bool aliveU = (tile_c*16 + 15) >= k;
    if (k > 0 && aliveU) {
      const float* pwp = &prowbuf[(k-1) & 1][pb];
      float4 P0 = *(const float4*)&pwp[0];
      float4 P1 = *(const float4*)&pwp[4];
      float4 P2 = *(const float4*)&pwp[8];
      float4 P3 = *(const float4*)&pwp[12];
#define UPD(R) { float mr = m##R; \
  M##R##_0.x -= mr*P0.x; M##R##_0.y -= mr*P0.y; M##R##_0.z -= mr*P0.z; M##R##_0.w -= mr*P0.w; \
  M##R##_1.x -= mr*P1.x; M##R##_1.y -= mr*P1.y; M##R##_1.z -= mr*P1.z; M##R##_1.w -= mr*P1.w; \
  M##R##_2.x -= mr*P2.x; M##R##_2.y -= mr*P2.y; M##R##_2.z -= mr*P2.z; M##R##_2.w -= mr*P2.w; \
  M##R##_3.x -= mr*P3.x; M##R##_3.y -= mr*P3.y; M##R##_3.z -= mr*P3.z; M##R##_3.w -= mr*P3.w; }
      REP8(UPD)
#undef UPD
    }
    // ---- pivot search ----
    unsigned b0 = (um & 1u) ? 0u : ((__float_as_uint(fabsf(cv.x)) & 0xFFFFFF00u) | (unsigned)(4*lane+0));
    unsigned b1 = (um & 2u) ? 0u : ((__float_as_uint(fabsf(cv.y)) & 0xFFFFFF00u) | (unsigned)(4*lane+1));
    unsigned b2 = (um & 4u) ? 0u : ((__float_as_uint(fabsf(cv.z)) & 0xFFFFFF00u) | (unsigned)(4*lane+2));
    unsigned b3 = (um & 8u) ? 0u : ((__float_as_uint(fabsf(cv.w)) & 0xFFFFFF00u) | (unsigned)(4*lane+3));
    unsigned bb = max(max(b0,b1), max(b2,b3));
    DPPMAX(bb, 0x111) DPPMAX(bb, 0x112) DPPMAX(bb, 0x114) DPPMAX(bb, 0x118)
    DPPMAX(bb, 0x142) DPPMAX(bb, 0x143)
    bb = (unsigned)__builtin_amdgcn_readlane((int)bb, 63);
    int p = (int)(bb & 255u);
    int wl = p >> 2, cc = p & 3;
    unsigned px = (unsigned)__builtin_amdgcn_readlane((int)__float_as_uint(cv.x), wl);
    unsigned py = (unsigned)__builtin_amdgcn_readlane((int)__float_as_uint(cv.y), wl);
    unsigned pz = (unsigned)__builtin_amdgcn_readlane((int)__float_as_uint(cv.z), wl);
    unsigned pw = (unsigned)__builtin_amdgcn_readlane((int)__float_as_uint(cv.w), wl);
    float piv = __uint_as_float(cc==0 ? px : cc==1 ? py : cc==2 ? pz : pw);
    int ee; float mant = frexpf(fabsf(piv), &ee);
    prod *= mant; esum += ee;
    int e2; prod = frexpf(prod, &e2); esum += e2;
    if (wl == lane) um |= 1u << cc;
    if (k == 255) break;
    float rp = 1.0f / piv;
    m0 = ca.x*rp; m1 = ca.y*rp; m2 = ca.z*rp; m3 = ca.w*rp;
    m4 = cb2.x*rp; m5 = cb2.y*rp; m6 = cb2.z*rp; m7 = cb2.w*rp;
    bool aliveK = (tile_c*16 + 15) > k;
    // ---- publish pivot row k (post-update-(k-1) registers) ----
    if (aliveK && tile_r == (p >> 3)) {
      float* pw_ = &prowbuf[k & 1][pb];
      switch (p & 7) {
#define PUBC(R) case R: *(float4*)&pw_[0] = M##R##_0; *(float4*)&pw_[4] = M##R##_1; \
                        *(float4*)&pw_[8] = M##R##_2; *(float4*)&pw_[12] = M##R##_3; break;
        REP8(PUBC)
#undef PUBC
      }
    }
    // ---- extract column k+1 (owning half-wave; pivot elem via shfl) ----
    int kn = k + 1;
    if (tile_c == (kn >> 4)) {
      float e0,e1,e2b,e3,e4,e5,e6,e7;
      switch (kn & 15) {
#define EXTC(I, G, C) case I: e0=M0_##G.C; e1=M1_##G.C; e2b=M2_##G.C; e3=M3_##G.C; \
                              e4=M4_##G.C; e5=M5_##G.C; e6=M6_##G.C; e7=M7_##G.C; break;
        EXTC(0,0,x) EXTC(1,0,y) EXTC(2,0,z) EXTC(3,0,w)
        EXTC(4,1,x) EXTC(5,1,y) EXTC(6,1,z) EXTC(7,1,w)
        EXTC(8,2,x) EXTC(9,2,y) EXTC(10,2,z) EXTC(11,2,w)
        EXTC(12,3,x) EXTC(13,3,y) EXTC(14,3,z) EXTC(15,3,w)
#undef EXTC
      }
      float sel;
      switch (p & 7) {
        case 0: sel = e0; break; case 1: sel = e1; break;
        case 2: sel = e2b; break; case 3: sel = e3; break;
        case 4: sel = e4; break; case 5: sel = e5; break;
        case 6: sel = e6; break; default: sel = e7; break;
      }
      float pv = __shfl(sel, (tile_c & 1)*32 + (p >> 3), 64);
      float4 w0, w1;
      w0.x = e0 - m0*pv; w0.y = e1 - m1*pv; w0.z = e2b - m2*pv; w0.w = e3 - m3*pv;
      w1.x = e4 - m4*pv; w1.y = e5 - m5*pv; w1.z = e6 - m6*pv; w1.w = e7 - m7*pv;
      *(float4*)&colbuf[kn & 1][br] = w0;
      *(float4*)&colbuf[kn & 1][br+4] = w1;
    }
    __syncthreads();
  }
  if (t == 0) g_logs[blockIdx.x] = logf(prod) + (float)esum * 0.69314718055994531f;
}

__global__ void k_final(float* out) { out[0] = g_logs[0] + g_logs[1]; }

// ---------------- launch ----------------
extern "C" void kernel_launch(void* const* d_in, const int* in_sizes, int n_in,
                              void* d_out, int out_size, void* d_ws, size_t ws_size,
                              hipStream_t stream) {
  const float* r     = (const float*)d_in[0];
  const float* a     = (const float*)d_in[1];
  const float* V0_W  = (const float*)d_in[2];
  const float* V0_b  = (const float*)d_in[3];
  const float* Vr_W  = (const float*)d_in[4];
  const float* Vr_b  = (const float*)d_in[5];
  const float* W0_W  = (const float*)d_in[6];
  const float* W0_b  = (const float*)d_in[7];
  const float* Wr_W  = (const float*)d_in[8];
  const float* Wr_b  = (const float*)d_in[9];
  const float* Vhu_W = (const float*)d_in[10];
  const float* Vhu_b = (const float*)d_in[11];
  const float* Vhd_W = (const float*)d_in[12];
  const float* Vhd_b = (const float*)d_in[13];
  const float* wu_W  = (const float*)d_in[14];
  const float* wu_b  = (const float*)d_in[15];
  const float* wd_W  = (const float*)d_in[16];
  const float* wd_b  = (const float*)d_in[17];
  float* out = (float*)d_out;

  k_pgeom<<<512, 256, 0, stream>>>(r, a);

  // layer 0 (smm + pup fused)
  k_layer<0,0,4,64,64><<<1152, 256, 0, stream>>>(V0_W, V0_b, W0_W, W0_b, r, 0, 0);
  k_reduce<<<258, 256, 0, stream>>>(0);
  // layer 1
  k_layer<1,1,64,256,256><<<1152, 256, 0, stream>>>(Vr_W + 0*896*256, Vr_b + 0,
                                                    Wr_W + 0*4096, Wr_b + 0, r, 0, 1);
  k_reduce<<<258, 256, 0, stream>>>(1);
  // layer 2
  k_layer<2,1,64,256,256><<<1152, 256, 0, stream>>>(Vr_W + 1*896*256, Vr_b + 256,
                                                    Wr_W + 1*4096, Wr_b + 64, r, 1, 0);
  k_reduce<<<258, 256, 0, stream>>>(0);
  // layer 3 (p4 not stored; only its means)
  k_layer<3,2,64,256,256><<<1152, 256, 0, stream>>>(Vr_W + 2*896*256, Vr_b + 512,
                                                    Wr_W + 2*4096, Wr_b + 128, r, 0, 0);
  k_reduce<<<258, 256, 0, stream>>>(1);
  // fused heads (u + d in one dispatch)
  k_smm<64,256,256><<<dim3(16,8), 256, 0, stream>>>(4, Vhu_W, Vhu_b, Vhd_W, Vhd_b);
  // fused orbitals (u + d in one dispatch)
  k_smm<0,256,0><<<dim3(16,8), 256, 0, stream>>>(6, wu_W, wu_b, wd_W, wd_b);
  // log|det| x2 and combine
  k_lu<<<2, 512, 0, stream>>>();
  k_final<<<1, 1, 0, stream>>>(out);
}